// Round 2
// baseline (8431.458 us; speedup 1.0000x reference)
//
#include <hip/hip_runtime.h>
#include <math.h>

#define S_LEN 1024
#define DMODEL 1024
#define NHEAD 16
#define DHEAD 64
#define NLAYER 4
#define FFDIM 4096
#define WIN_HALF 128
#define NEGINF -1e9f
#define LN_EPS 1e-5f

// ---------------------------------------------------------------- LayerNorm
__global__ __launch_bounds__(256) void ln_kernel(
    const float* __restrict__ x, const float* __restrict__ g,
    const float* __restrict__ b, float* __restrict__ y) {
  __shared__ float red[8];
  const int row = blockIdx.x;
  const int t = threadIdx.x;
  const float4* xr = (const float4*)(x + (size_t)row * DMODEL);
  float4 v = xr[t];
  float s = v.x + v.y + v.z + v.w;
  float ss = v.x * v.x + v.y * v.y + v.z * v.z + v.w * v.w;
#pragma unroll
  for (int o = 32; o > 0; o >>= 1) {
    s += __shfl_down(s, o);
    ss += __shfl_down(ss, o);
  }
  const int wid = t >> 6;
  if ((t & 63) == 0) { red[wid] = s; red[4 + wid] = ss; }
  __syncthreads();
  if (t == 0) {
    float S1 = red[0] + red[1] + red[2] + red[3];
    float S2 = red[4] + red[5] + red[6] + red[7];
    float m = S1 * (1.0f / DMODEL);
    float var = S2 * (1.0f / DMODEL) - m * m;
    red[0] = m;
    red[1] = rsqrtf(var + LN_EPS);
  }
  __syncthreads();
  const float m = red[0], inv = red[1];
  float4 gv = ((const float4*)g)[t];
  float4 bv = ((const float4*)b)[t];
  float4 o;
  o.x = (v.x - m) * inv * gv.x + bv.x;
  o.y = (v.y - m) * inv * gv.y + bv.y;
  o.z = (v.z - m) * inv * gv.z + bv.z;
  o.w = (v.w - m) * inv * gv.w + bv.w;
  ((float4*)(y + (size_t)row * DMODEL))[t] = o;
}

// ---------------------------------------------------------------- SGEMM
// C[M,N] = A[M,K] @ W[K,N]  (+bias) (+GELU) (+=C)
// flags: 1 = GELU, 2 = accumulate into C
// 256 threads as 16x16; per-thread microtile (BM/16)x(BN/16), split-quadrant
// layout so LDS reads are float4. Requires M%BM==0, N%BN==0, K%16==0.
#define BK 16

__device__ __forceinline__ float gelu_exact(float x) {
  return 0.5f * x * (1.0f + erff(x * 0.70710678118654752f));
}

template <int BM, int BN>
__global__ __launch_bounds__(256) void gemm_kernel(
    const float* __restrict__ A, const float* __restrict__ W,
    const float* __restrict__ bias, float* __restrict__ C,
    int M, int N, int K, int flags) {
  constexpr int GM = BM / 64;  // 4-row groups per thread (1 or 2)
  constexpr int GN = BN / 64;
  __shared__ float As[BK][BM + 4];  // row stride (BM+4)*4B is 16B-multiple
  __shared__ float Bs[BK][BN + 4];

  const int tid = threadIdx.x;
  const int tx = tid & 15, ty = tid >> 4;
  const int row0 = blockIdx.y * BM, col0 = blockIdx.x * BN;

  float acc[GM * 4][GN * 4] = {};

  for (int kt = 0; kt < K; kt += BK) {
    // load A tile (BM x 16), transpose into As[k][m]
#pragma unroll
    for (int p = 0; p < BM * BK / 1024; p++) {
      const int idx = tid + p * 256;
      const int m = idx >> 2;
      const int k4 = (idx & 3) * 4;
      float4 av = *(const float4*)(A + (size_t)(row0 + m) * K + kt + k4);
      As[k4 + 0][m] = av.x;
      As[k4 + 1][m] = av.y;
      As[k4 + 2][m] = av.z;
      As[k4 + 3][m] = av.w;
    }
    // load B tile (16 x BN)
#pragma unroll
    for (int p = 0; p < BK * BN / 1024; p++) {
      const int idx = tid + p * 256;
      const int r = idx / (BN / 4);
      const int c = (idx % (BN / 4)) * 4;
      float4 bv = *(const float4*)(W + (size_t)(kt + r) * N + col0 + c);
      *(float4*)&Bs[r][c] = bv;
    }
    __syncthreads();
#pragma unroll
    for (int kk = 0; kk < BK; kk++) {
      float af[GM * 4], bf[GN * 4];
#pragma unroll
      for (int g = 0; g < GM; g++) {
        float4 a = *(const float4*)&As[kk][g * 64 + ty * 4];
        af[g * 4 + 0] = a.x; af[g * 4 + 1] = a.y;
        af[g * 4 + 2] = a.z; af[g * 4 + 3] = a.w;
      }
#pragma unroll
      for (int g = 0; g < GN; g++) {
        float4 b = *(const float4*)&Bs[kk][g * 64 + tx * 4];
        bf[g * 4 + 0] = b.x; bf[g * 4 + 1] = b.y;
        bf[g * 4 + 2] = b.z; bf[g * 4 + 3] = b.w;
      }
#pragma unroll
      for (int i = 0; i < GM * 4; i++)
#pragma unroll
        for (int j = 0; j < GN * 4; j++) acc[i][j] += af[i] * bf[j];
    }
    __syncthreads();
  }

  const int do_gelu = flags & 1;
  const int do_acc = flags & 2;
#pragma unroll
  for (int i = 0; i < GM * 4; i++) {
    const int row = row0 + (i >> 2) * (BM / 2) + ty * 4 + (i & 3);
#pragma unroll
    for (int gn = 0; gn < GN; gn++) {
      const int col = col0 + gn * (BN / 2) + tx * 4;
      float4 c = make_float4(acc[i][gn * 4 + 0], acc[i][gn * 4 + 1],
                             acc[i][gn * 4 + 2], acc[i][gn * 4 + 3]);
      if (bias) {
        float4 bb = *(const float4*)(bias + col);
        c.x += bb.x; c.y += bb.y; c.z += bb.z; c.w += bb.w;
      }
      if (do_gelu) {
        c.x = gelu_exact(c.x); c.y = gelu_exact(c.y);
        c.z = gelu_exact(c.z); c.w = gelu_exact(c.w);
      }
      float* crow = C + (size_t)row * N + col;
      if (do_acc) {
        float4 old = *(const float4*)crow;
        c.x += old.x; c.y += old.y; c.z += old.z; c.w += old.w;
      }
      *(float4*)crow = c;
    }
  }
}

// ---------------------------------------------------------------- Attention
// One block per (q, h, b). Scores for the full row live in LDS (4 KB).
// qkv layout per token row (3*DMODEL): [q(16x64) | k | v] with head-major 64.
__global__ __launch_bounds__(256) void attn_kernel(
    const float* __restrict__ qkv, const float* __restrict__ bias,
    float* __restrict__ out, int use_window) {
  __shared__ float sc[S_LEN];
  __shared__ float4 qs[DHEAD / 4];
  __shared__ float red[8];
  __shared__ float pbuf[4][DHEAD];

  const int q = blockIdx.x, h = blockIdx.y, b = blockIdx.z;
  const int t = threadIdx.x;

  const float* qrow = qkv + (size_t)(b * S_LEN + q) * (3 * DMODEL) + h * DHEAD;
  if (t < 16) qs[t] = ((const float4*)qrow)[t];
  __syncthreads();

  const int lo = use_window ? max(0, q - WIN_HALF) : 0;
  const int kb_lo = lo >> 8, kb_hi = q >> 8;

  const float* brow = bias + ((size_t)(b * NHEAD + h) * S_LEN + q) * S_LEN;

  float lmax = -INFINITY;
  for (int kb = kb_lo; kb <= kb_hi; kb++) {
    const int k = (kb << 8) + t;
    const float4* kp =
        (const float4*)(qkv + (size_t)(b * S_LEN + k) * (3 * DMODEL) + DMODEL + h * DHEAD);
    float s = 0.f;
#pragma unroll
    for (int i = 0; i < 16; i++) {
      float4 kv = kp[i];
      float4 qv = qs[i];
      s += qv.x * kv.x + qv.y * kv.y + qv.z * kv.z + qv.w * kv.w;
    }
    s = s * 0.125f + brow[k];
    if (k > q) s += NEGINF;
    if (use_window && (k - q > WIN_HALF || q - k > WIN_HALF)) s += NEGINF;
    sc[k] = s;
    lmax = fmaxf(lmax, s);
  }
#pragma unroll
  for (int o = 32; o > 0; o >>= 1) lmax = fmaxf(lmax, __shfl_down(lmax, o));
  if ((t & 63) == 0) red[t >> 6] = lmax;
  __syncthreads();
  if (t == 0) red[0] = fmaxf(fmaxf(red[0], red[1]), fmaxf(red[2], red[3]));
  __syncthreads();
  const float m = red[0];

  float lsum = 0.f;
  for (int kb = kb_lo; kb <= kb_hi; kb++) {
    const int k = (kb << 8) + t;
    float e = __expf(sc[k] - m);
    sc[k] = e;
    lsum += e;
  }
#pragma unroll
  for (int o = 32; o > 0; o >>= 1) lsum += __shfl_down(lsum, o);
  if ((t & 63) == 0) red[4 + (t >> 6)] = lsum;
  __syncthreads();  // covers sc[] writes AND red[] writes
  const float inv = 1.0f / (red[4] + red[5] + red[6] + red[7]);

  // PV: part p covers k in [p*256, p*256+255] intersected with [lo, q]
  const int d = t & 63, part = t >> 6;
  const float* vbase = qkv + 2 * DMODEL + h * DHEAD + d;
  float o_ = 0.f;
  const int kst = max(lo, part << 8);
  const int ken = min(q, (part << 8) + 255);
  for (int kk = kst; kk <= ken; kk++) {
    o_ += sc[kk] * vbase[(size_t)(b * S_LEN + kk) * (3 * DMODEL)];
  }
  pbuf[part][d] = o_;
  __syncthreads();
  if (t < DHEAD) {
    float r = (pbuf[0][t] + pbuf[1][t] + pbuf[2][t] + pbuf[3][t]) * inv;
    out[(size_t)(b * S_LEN + q) * DMODEL + h * DHEAD + t] = r;
  }
}

// ---------------------------------------------------------------- Head + gate
__global__ __launch_bounds__(256) void head_kernel(
    const float* __restrict__ h, const float* __restrict__ t1,
    const float* __restrict__ w2, const float* __restrict__ b2,
    const float* __restrict__ gate_w, const float* __restrict__ gate_b,
    const float* __restrict__ gatec_w, const float* __restrict__ gatec_b,
    float* __restrict__ out) {
  __shared__ float redm[4][8];
  const int row = blockIdx.x;
  const int t = threadIdx.x;
  const float* hrow = h + (size_t)row * DMODEL;
  const float* trow = t1 + (size_t)row * (DMODEL / 2);

  float p[8] = {0, 0, 0, 0, 0, 0, 0, 0};
  for (int i = t; i < DMODEL / 2; i += 256) {
    float tv = trow[i];
#pragma unroll
    for (int j = 0; j < 7; j++) p[j] += tv * w2[i * 7 + j];
  }
  for (int i = t; i < DMODEL; i += 256) p[7] += hrow[i] * gate_w[i];

#pragma unroll
  for (int j = 0; j < 8; j++) {
#pragma unroll
    for (int o = 32; o > 0; o >>= 1) p[j] += __shfl_down(p[j], o);
  }
  const int wid = t >> 6;
  if ((t & 63) == 0) {
#pragma unroll
    for (int j = 0; j < 8; j++) redm[wid][j] = p[j];
  }
  __syncthreads();

  float raw[7], gd = 0.f;
#pragma unroll
  for (int j = 0; j < 7; j++)
    raw[j] = redm[0][j] + redm[1][j] + redm[2][j] + redm[3][j] + b2[j];
  gd = redm[0][7] + redm[1][7] + redm[2][7] + redm[3][7] + gate_b[0];

  float sig[7];
#pragma unroll
  for (int j = 0; j < 7; j++) sig[j] = 1.0f / (1.0f + __expf(-raw[j]));
  const float learned = 1.0f / (1.0f + __expf(-gd));
  const float s2v = tanhf(raw[2]) * 2.0f;
  const float gate =
      1.0f / (1.0f + __expf(-(learned * gatec_w[0] + sig[0] * gatec_w[1] + gatec_b[0])));

  float* orow = out + (size_t)row * (DMODEL + 8);
  float4 hv = ((const float4*)hrow)[t];
  *(float4*)(orow + t * 4) = hv;
  if (t == 0) {
    orow[DMODEL + 0] = sig[0];
    orow[DMODEL + 1] = sig[1];
    orow[DMODEL + 2] = s2v;
    orow[DMODEL + 3] = sig[3];
    orow[DMODEL + 4] = sig[4];
    orow[DMODEL + 5] = sig[5];
    orow[DMODEL + 6] = sig[6];
    orow[DMODEL + 7] = gate;
  }
}

// ---------------------------------------------------------------- launch
extern "C" void kernel_launch(void* const* d_in, const int* in_sizes, int n_in,
                              void* d_out, int out_size, void* d_ws, size_t ws_size,
                              hipStream_t stream) {
  const float* x = (const float*)d_in[0];
  const float* tb = (const float*)d_in[1];
  const float* qkv_w = (const float*)d_in[2];
  const float* out_w = (const float*)d_in[3];
  const float* w1 = (const float*)d_in[4];
  const float* b1 = (const float*)d_in[5];
  const float* w2 = (const float*)d_in[6];
  const float* b2 = (const float*)d_in[7];
  const float* ln1_g = (const float*)d_in[8];
  const float* ln1_b = (const float*)d_in[9];
  const float* ln2_g = (const float*)d_in[10];
  const float* ln2_b = (const float*)d_in[11];
  const float* head_ln_g = (const float*)d_in[12];
  const float* head_ln_b = (const float*)d_in[13];
  const float* head_w1 = (const float*)d_in[14];
  const float* head_b1 = (const float*)d_in[15];
  const float* head_w2 = (const float*)d_in[16];
  const float* head_b2 = (const float*)d_in[17];
  const float* gate_w = (const float*)d_in[18];
  const float* gate_b = (const float*)d_in[19];
  const float* gatec_w = (const float*)d_in[20];
  const float* gatec_b = (const float*)d_in[21];

  const size_t NTOK = 2 * S_LEN;              // 2048 rows
  const size_t SZ_BSD = NTOK * DMODEL;        // 2,097,152 floats

  float* ws = (float*)d_ws;
  float* h = ws;                   // [B,S,D]
  float* y = h + SZ_BSD;           // [B,S,D]
  float* attno = y + SZ_BSD;       // [B,S,D]
  float* big = attno + SZ_BSD;     // qkv [B,S,3D] / ffn1 [B,S,FF]
  float* t1 = big + NTOK * FFDIM;  // [B,S,D/2]

  hipMemcpyAsync(h, x, SZ_BSD * sizeof(float), hipMemcpyDeviceToDevice, stream);

  for (int l = 0; l < NLAYER; l++) {
    ln_kernel<<<NTOK, 256, 0, stream>>>(h, ln1_g + l * DMODEL, ln1_b + l * DMODEL, y);
    gemm_kernel<128, 128><<<dim3(3 * DMODEL / 128, NTOK / 128), 256, 0, stream>>>(
        y, qkv_w + (size_t)l * DMODEL * 3 * DMODEL, nullptr, big,
        NTOK, 3 * DMODEL, DMODEL, 0);
    attn_kernel<<<dim3(S_LEN, NHEAD, 2), 256, 0, stream>>>(
        big, tb, attno, (l % 2 == 0) ? 1 : 0);
    gemm_kernel<128, 64><<<dim3(DMODEL / 64, NTOK / 128), 256, 0, stream>>>(
        attno, out_w + (size_t)l * DMODEL * DMODEL, nullptr, h,
        NTOK, DMODEL, DMODEL, 2);
    ln_kernel<<<NTOK, 256, 0, stream>>>(h, ln2_g + l * DMODEL, ln2_b + l * DMODEL, y);
    gemm_kernel<128, 128><<<dim3(FFDIM / 128, NTOK / 128), 256, 0, stream>>>(
        y, w1 + (size_t)l * DMODEL * FFDIM, b1 + (size_t)l * FFDIM, big,
        NTOK, FFDIM, DMODEL, 1);
    gemm_kernel<128, 64><<<dim3(DMODEL / 64, NTOK / 128), 256, 0, stream>>>(
        big, w2 + (size_t)l * FFDIM * DMODEL, b2 + (size_t)l * DMODEL, h,
        NTOK, DMODEL, FFDIM, 2);
  }

  ln_kernel<<<NTOK, 256, 0, stream>>>(h, head_ln_g, head_ln_b, y);
  gemm_kernel<64, 64><<<dim3((DMODEL / 2) / 64, NTOK / 64), 256, 0, stream>>>(
      y, head_w1, head_b1, t1, NTOK, DMODEL / 2, DMODEL, 1);
  head_kernel<<<NTOK, 256, 0, stream>>>(h, t1, head_w2, head_b2,
                                        gate_w, gate_b, gatec_w, gatec_b,
                                        (float*)d_out);
}

// Round 3
// 4597.099 us; speedup vs baseline: 1.8341x; 1.8341x over previous
//
#include <hip/hip_runtime.h>
#include <math.h>

#define S_LEN 1024
#define DMODEL 1024
#define NHEAD 16
#define DHEAD 64
#define NLAYER 4
#define FFDIM 4096
#define WIN_HALF 128
#define NEGINF -1e9f
#define LN_EPS 1e-5f

// ---------------------------------------------------------------- LayerNorm
__global__ __launch_bounds__(256) void ln_kernel(
    const float* __restrict__ x, const float* __restrict__ g,
    const float* __restrict__ b, float* __restrict__ y) {
  __shared__ float red[8];
  const int row = blockIdx.x;
  const int t = threadIdx.x;
  const float4* xr = (const float4*)(x + (size_t)row * DMODEL);
  float4 v = xr[t];
  float s = v.x + v.y + v.z + v.w;
  float ss = v.x * v.x + v.y * v.y + v.z * v.z + v.w * v.w;
#pragma unroll
  for (int o = 32; o > 0; o >>= 1) {
    s += __shfl_down(s, o);
    ss += __shfl_down(ss, o);
  }
  const int wid = t >> 6;
  if ((t & 63) == 0) { red[wid] = s; red[4 + wid] = ss; }
  __syncthreads();
  if (t == 0) {
    float S1 = red[0] + red[1] + red[2] + red[3];
    float S2 = red[4] + red[5] + red[6] + red[7];
    float m = S1 * (1.0f / DMODEL);
    float var = S2 * (1.0f / DMODEL) - m * m;
    red[0] = m;
    red[1] = rsqrtf(var + LN_EPS);
  }
  __syncthreads();
  const float m = red[0], inv = red[1];
  float4 gv = ((const float4*)g)[t];
  float4 bv = ((const float4*)b)[t];
  float4 o;
  o.x = (v.x - m) * inv * gv.x + bv.x;
  o.y = (v.y - m) * inv * gv.y + bv.y;
  o.z = (v.z - m) * inv * gv.z + bv.z;
  o.w = (v.w - m) * inv * gv.w + bv.w;
  ((float4*)(y + (size_t)row * DMODEL))[t] = o;
}

// ---------------------------------------------------------------- SGEMM
// C[M,N] = A[M,K] @ W[K,N]  (+bias) (+GELU) (+=C)
// flags: 1 = GELU, 2 = accumulate into C
#define BK 16

__device__ __forceinline__ float gelu_exact(float x) {
  return 0.5f * x * (1.0f + erff(x * 0.70710678118654752f));
}

template <int BM, int BN>
__global__ __launch_bounds__(256) void gemm_kernel(
    const float* __restrict__ A, const float* __restrict__ W,
    const float* __restrict__ bias, float* __restrict__ C,
    int M, int N, int K, int flags) {
  constexpr int GM = BM / 64;
  constexpr int GN = BN / 64;
  __shared__ float As[BK][BM + 4];
  __shared__ float Bs[BK][BN + 4];

  const int tid = threadIdx.x;
  const int tx = tid & 15, ty = tid >> 4;
  const int row0 = blockIdx.y * BM, col0 = blockIdx.x * BN;

  float acc[GM * 4][GN * 4] = {};

  for (int kt = 0; kt < K; kt += BK) {
#pragma unroll
    for (int p = 0; p < BM * BK / 1024; p++) {
      const int idx = tid + p * 256;
      const int m = idx >> 2;
      const int k4 = (idx & 3) * 4;
      float4 av = *(const float4*)(A + (size_t)(row0 + m) * K + kt + k4);
      As[k4 + 0][m] = av.x;
      As[k4 + 1][m] = av.y;
      As[k4 + 2][m] = av.z;
      As[k4 + 3][m] = av.w;
    }
#pragma unroll
    for (int p = 0; p < BK * BN / 1024; p++) {
      const int idx = tid + p * 256;
      const int r = idx / (BN / 4);
      const int c = (idx % (BN / 4)) * 4;
      float4 bv = *(const float4*)(W + (size_t)(kt + r) * N + col0 + c);
      *(float4*)&Bs[r][c] = bv;
    }
    __syncthreads();
#pragma unroll
    for (int kk = 0; kk < BK; kk++) {
      float af[GM * 4], bf[GN * 4];
#pragma unroll
      for (int g = 0; g < GM; g++) {
        float4 a = *(const float4*)&As[kk][g * 64 + ty * 4];
        af[g * 4 + 0] = a.x; af[g * 4 + 1] = a.y;
        af[g * 4 + 2] = a.z; af[g * 4 + 3] = a.w;
      }
#pragma unroll
      for (int g = 0; g < GN; g++) {
        float4 b = *(const float4*)&Bs[kk][g * 64 + tx * 4];
        bf[g * 4 + 0] = b.x; bf[g * 4 + 1] = b.y;
        bf[g * 4 + 2] = b.z; bf[g * 4 + 3] = b.w;
      }
#pragma unroll
      for (int i = 0; i < GM * 4; i++)
#pragma unroll
        for (int j = 0; j < GN * 4; j++) acc[i][j] += af[i] * bf[j];
    }
    __syncthreads();
  }

  const int do_gelu = flags & 1;
  const int do_acc = flags & 2;
#pragma unroll
  for (int i = 0; i < GM * 4; i++) {
    const int row = row0 + (i >> 2) * (BM / 2) + ty * 4 + (i & 3);
#pragma unroll
    for (int gn = 0; gn < GN; gn++) {
      const int col = col0 + gn * (BN / 2) + tx * 4;
      float4 c = make_float4(acc[i][gn * 4 + 0], acc[i][gn * 4 + 1],
                             acc[i][gn * 4 + 2], acc[i][gn * 4 + 3]);
      if (bias) {
        float4 bb = *(const float4*)(bias + col);
        c.x += bb.x; c.y += bb.y; c.z += bb.z; c.w += bb.w;
      }
      if (do_gelu) {
        c.x = gelu_exact(c.x); c.y = gelu_exact(c.y);
        c.z = gelu_exact(c.z); c.w = gelu_exact(c.w);
      }
      float* crow = C + (size_t)row * N + col;
      if (do_acc) {
        float4 old = *(const float4*)crow;
        c.x += old.x; c.y += old.y; c.z += old.z; c.w += old.w;
      }
      *(float4*)crow = c;
    }
  }
}

// ---------------------------------------------------------------- Flash attention (fp32)
// Block = (64-query tile, head, batch). 256 threads as 16x16.
// Qs/KVs transposed [d][row] for QK^T; V staged into KVs (time-shared) for PV.
// Online softmax fully in registers (row state redundant across the row's 16 lanes).
__global__ __launch_bounds__(256) void fattn_kernel(
    const float* __restrict__ qkv, const float* __restrict__ bias,
    float* __restrict__ out, int use_window) {
  __shared__ float Qs[64][68];   // [d][q]
  __shared__ float KVs[64][68];  // phase 1: [d][k]  phase 2: [k][d]
  __shared__ float Ps[64][67];   // [k][q]

  const int b = blockIdx.z, h = blockIdx.y;
  // pair heavy/light q-tiles across the two batch halves for CU load balance
  const int qt = (b == 0) ? blockIdx.x : ((int)gridDim.x - 1 - (int)blockIdx.x);
  const int q0 = qt << 6;
  const int tid = threadIdx.x;
  const int tx = tid & 15, ty = tid >> 4;

  const float* qbase = qkv + (size_t)b * S_LEN * (3 * DMODEL) + h * DHEAD;
  const float* kbase = qbase + DMODEL;
  const float* vbase = qbase + 2 * DMODEL;
  const float* bbase = bias + (size_t)(b * NHEAD + h) * S_LEN * S_LEN;

#pragma unroll
  for (int p = 0; p < 4; p++) {
    const int idx = tid + p * 256;
    const int row = idx >> 4, c4 = (idx & 15) * 4;
    float4 v = *(const float4*)(qbase + (size_t)(q0 + row) * (3 * DMODEL) + c4);
    Qs[c4 + 0][row] = v.x; Qs[c4 + 1][row] = v.y;
    Qs[c4 + 2][row] = v.z; Qs[c4 + 3][row] = v.w;
  }

  float O[4][4] = {};
  float mr[4] = {-1e30f, -1e30f, -1e30f, -1e30f};
  float lr[4] = {0.f, 0.f, 0.f, 0.f};

  const int lo_t = use_window ? (max(0, q0 - WIN_HALF) >> 6) : 0;
  const int hi_t = q0 >> 6;

  for (int kt = lo_t; kt <= hi_t; kt++) {
    const int k0 = kt << 6;
    __syncthreads();  // previous PV done with KVs/Ps
    // stage K transposed: KVs[d][k]
#pragma unroll
    for (int p = 0; p < 4; p++) {
      const int idx = tid + p * 256;
      const int row = idx >> 4, c4 = (idx & 15) * 4;
      float4 kv = *(const float4*)(kbase + (size_t)(k0 + row) * (3 * DMODEL) + c4);
      KVs[c4 + 0][row] = kv.x; KVs[c4 + 1][row] = kv.y;
      KVs[c4 + 2][row] = kv.z; KVs[c4 + 3][row] = kv.w;
    }
    __syncthreads();

    // QK^T: acc[r][j] = S[q0+ty*4+r][k0+tx*4+j]
    float acc[4][4] = {};
#pragma unroll 16
    for (int dd = 0; dd < 64; dd++) {
      float4 a = *(const float4*)&Qs[dd][ty * 4];
      float4 kv = *(const float4*)&KVs[dd][tx * 4];
      acc[0][0] += a.x * kv.x; acc[0][1] += a.x * kv.y; acc[0][2] += a.x * kv.z; acc[0][3] += a.x * kv.w;
      acc[1][0] += a.y * kv.x; acc[1][1] += a.y * kv.y; acc[1][2] += a.y * kv.z; acc[1][3] += a.y * kv.w;
      acc[2][0] += a.z * kv.x; acc[2][1] += a.z * kv.y; acc[2][2] += a.z * kv.z; acc[2][3] += a.z * kv.w;
      acc[3][0] += a.w * kv.x; acc[3][1] += a.w * kv.y; acc[3][2] += a.w * kv.z; acc[3][3] += a.w * kv.w;
    }

    // bias + masks + online softmax (register state, shfl row-reduce)
#pragma unroll
    for (int r = 0; r < 4; r++) {
      const int q = q0 + ty * 4 + r;
      float4 bb = *(const float4*)(bbase + (size_t)q * S_LEN + k0 + tx * 4);
      float s0 = acc[r][0] * 0.125f + bb.x;
      float s1 = acc[r][1] * 0.125f + bb.y;
      float s2 = acc[r][2] * 0.125f + bb.z;
      float s3 = acc[r][3] * 0.125f + bb.w;
      const int kb = k0 + tx * 4;
      if (kb + 0 > q || (use_window && q - (kb + 0) > WIN_HALF)) s0 = -1e30f;
      if (kb + 1 > q || (use_window && q - (kb + 1) > WIN_HALF)) s1 = -1e30f;
      if (kb + 2 > q || (use_window && q - (kb + 2) > WIN_HALF)) s2 = -1e30f;
      if (kb + 3 > q || (use_window && q - (kb + 3) > WIN_HALF)) s3 = -1e30f;

      float pm = fmaxf(fmaxf(s0, s1), fmaxf(s2, s3));
      pm = fmaxf(pm, __shfl_xor(pm, 1));
      pm = fmaxf(pm, __shfl_xor(pm, 2));
      pm = fmaxf(pm, __shfl_xor(pm, 4));
      pm = fmaxf(pm, __shfl_xor(pm, 8));
      const float mnew = fmaxf(mr[r], pm);
      const float alpha = __expf(mr[r] - mnew);
      mr[r] = mnew;
      const float p0 = __expf(s0 - mnew);
      const float p1 = __expf(s1 - mnew);
      const float p2 = __expf(s2 - mnew);
      const float p3 = __expf(s3 - mnew);
      float ps = p0 + p1 + p2 + p3;
      ps += __shfl_xor(ps, 1);
      ps += __shfl_xor(ps, 2);
      ps += __shfl_xor(ps, 4);
      ps += __shfl_xor(ps, 8);
      lr[r] = lr[r] * alpha + ps;
      O[r][0] *= alpha; O[r][1] *= alpha; O[r][2] *= alpha; O[r][3] *= alpha;
      const int qc = ty * 4 + r;
      Ps[tx * 4 + 0][qc] = p0;
      Ps[tx * 4 + 1][qc] = p1;
      Ps[tx * 4 + 2][qc] = p2;
      Ps[tx * 4 + 3][qc] = p3;
    }
    __syncthreads();  // GEMM1 reads of KVs done; Ps complete

    // stage V natural: KVs[k][d] (overwrites K — no longer needed)
#pragma unroll
    for (int p = 0; p < 4; p++) {
      const int idx = tid + p * 256;
      const int row = idx >> 4, c4 = (idx & 15) * 4;
      float4 vv = *(const float4*)(vbase + (size_t)(k0 + row) * (3 * DMODEL) + c4);
      *(float4*)&KVs[row][c4] = vv;
    }
    __syncthreads();

    // PV: O[r][j] += P^T[kk][q] * V[kk][d]
#pragma unroll 16
    for (int kk = 0; kk < 64; kk++) {
      const float p0 = Ps[kk][ty * 4 + 0];
      const float p1 = Ps[kk][ty * 4 + 1];
      const float p2 = Ps[kk][ty * 4 + 2];
      const float p3 = Ps[kk][ty * 4 + 3];
      float4 vv = *(const float4*)&KVs[kk][tx * 4];
      O[0][0] += p0 * vv.x; O[0][1] += p0 * vv.y; O[0][2] += p0 * vv.z; O[0][3] += p0 * vv.w;
      O[1][0] += p1 * vv.x; O[1][1] += p1 * vv.y; O[1][2] += p1 * vv.z; O[1][3] += p1 * vv.w;
      O[2][0] += p2 * vv.x; O[2][1] += p2 * vv.y; O[2][2] += p2 * vv.z; O[2][3] += p2 * vv.w;
      O[3][0] += p3 * vv.x; O[3][1] += p3 * vv.y; O[3][2] += p3 * vv.z; O[3][3] += p3 * vv.w;
    }
  }

#pragma unroll
  for (int r = 0; r < 4; r++) {
    const float inv = 1.0f / lr[r];
    float4 o4 = make_float4(O[r][0] * inv, O[r][1] * inv, O[r][2] * inv, O[r][3] * inv);
    *(float4*)(out + (size_t)(b * S_LEN + q0 + ty * 4 + r) * DMODEL + h * DHEAD + tx * 4) = o4;
  }
}

// ---------------------------------------------------------------- Head + gate
__global__ __launch_bounds__(256) void head_kernel(
    const float* __restrict__ h, const float* __restrict__ t1,
    const float* __restrict__ w2, const float* __restrict__ b2,
    const float* __restrict__ gate_w, const float* __restrict__ gate_b,
    const float* __restrict__ gatec_w, const float* __restrict__ gatec_b,
    float* __restrict__ out) {
  __shared__ float redm[4][8];
  const int row = blockIdx.x;
  const int t = threadIdx.x;
  const float* hrow = h + (size_t)row * DMODEL;
  const float* trow = t1 + (size_t)row * (DMODEL / 2);

  float p[8] = {0, 0, 0, 0, 0, 0, 0, 0};
  for (int i = t; i < DMODEL / 2; i += 256) {
    float tv = trow[i];
#pragma unroll
    for (int j = 0; j < 7; j++) p[j] += tv * w2[i * 7 + j];
  }
  for (int i = t; i < DMODEL; i += 256) p[7] += hrow[i] * gate_w[i];

#pragma unroll
  for (int j = 0; j < 8; j++) {
#pragma unroll
    for (int o = 32; o > 0; o >>= 1) p[j] += __shfl_down(p[j], o);
  }
  const int wid = t >> 6;
  if ((t & 63) == 0) {
#pragma unroll
    for (int j = 0; j < 8; j++) redm[wid][j] = p[j];
  }
  __syncthreads();

  float raw[7], gd = 0.f;
#pragma unroll
  for (int j = 0; j < 7; j++)
    raw[j] = redm[0][j] + redm[1][j] + redm[2][j] + redm[3][j] + b2[j];
  gd = redm[0][7] + redm[1][7] + redm[2][7] + redm[3][7] + gate_b[0];

  float sig[7];
#pragma unroll
  for (int j = 0; j < 7; j++) sig[j] = 1.0f / (1.0f + __expf(-raw[j]));
  const float learned = 1.0f / (1.0f + __expf(-gd));
  const float s2v = tanhf(raw[2]) * 2.0f;
  const float gate =
      1.0f / (1.0f + __expf(-(learned * gatec_w[0] + sig[0] * gatec_w[1] + gatec_b[0])));

  float* orow = out + (size_t)row * (DMODEL + 8);
  float4 hv = ((const float4*)hrow)[t];
  *(float4*)(orow + t * 4) = hv;
  if (t == 0) {
    orow[DMODEL + 0] = sig[0];
    orow[DMODEL + 1] = sig[1];
    orow[DMODEL + 2] = s2v;
    orow[DMODEL + 3] = sig[3];
    orow[DMODEL + 4] = sig[4];
    orow[DMODEL + 5] = sig[5];
    orow[DMODEL + 6] = sig[6];
    orow[DMODEL + 7] = gate;
  }
}

// ---------------------------------------------------------------- launch
extern "C" void kernel_launch(void* const* d_in, const int* in_sizes, int n_in,
                              void* d_out, int out_size, void* d_ws, size_t ws_size,
                              hipStream_t stream) {
  const float* x = (const float*)d_in[0];
  const float* tb = (const float*)d_in[1];
  const float* qkv_w = (const float*)d_in[2];
  const float* out_w = (const float*)d_in[3];
  const float* w1 = (const float*)d_in[4];
  const float* b1 = (const float*)d_in[5];
  const float* w2 = (const float*)d_in[6];
  const float* b2 = (const float*)d_in[7];
  const float* ln1_g = (const float*)d_in[8];
  const float* ln1_b = (const float*)d_in[9];
  const float* ln2_g = (const float*)d_in[10];
  const float* ln2_b = (const float*)d_in[11];
  const float* head_ln_g = (const float*)d_in[12];
  const float* head_ln_b = (const float*)d_in[13];
  const float* head_w1 = (const float*)d_in[14];
  const float* head_b1 = (const float*)d_in[15];
  const float* head_w2 = (const float*)d_in[16];
  const float* head_b2 = (const float*)d_in[17];
  const float* gate_w = (const float*)d_in[18];
  const float* gate_b = (const float*)d_in[19];
  const float* gatec_w = (const float*)d_in[20];
  const float* gatec_b = (const float*)d_in[21];

  const size_t NTOK = 2 * S_LEN;
  const size_t SZ_BSD = NTOK * DMODEL;

  float* ws = (float*)d_ws;
  float* h = ws;
  float* y = h + SZ_BSD;
  float* attno = y + SZ_BSD;
  float* big = attno + SZ_BSD;
  float* t1 = big + NTOK * FFDIM;

  hipMemcpyAsync(h, x, SZ_BSD * sizeof(float), hipMemcpyDeviceToDevice, stream);

  for (int l = 0; l < NLAYER; l++) {
    ln_kernel<<<NTOK, 256, 0, stream>>>(h, ln1_g + l * DMODEL, ln1_b + l * DMODEL, y);
    gemm_kernel<128, 128><<<dim3(3 * DMODEL / 128, NTOK / 128), 256, 0, stream>>>(
        y, qkv_w + (size_t)l * DMODEL * 3 * DMODEL, nullptr, big,
        NTOK, 3 * DMODEL, DMODEL, 0);
    fattn_kernel<<<dim3(S_LEN / 64, NHEAD, 2), 256, 0, stream>>>(
        big, tb, attno, (l % 2 == 0) ? 1 : 0);
    gemm_kernel<128, 64><<<dim3(DMODEL / 64, NTOK / 128), 256, 0, stream>>>(
        attno, out_w + (size_t)l * DMODEL * DMODEL, nullptr, h,
        NTOK, DMODEL, DMODEL, 2);
    ln_kernel<<<NTOK, 256, 0, stream>>>(h, ln2_g + l * DMODEL, ln2_b + l * DMODEL, y);
    gemm_kernel<128, 128><<<dim3(FFDIM / 128, NTOK / 128), 256, 0, stream>>>(
        y, w1 + (size_t)l * DMODEL * FFDIM, b1 + (size_t)l * FFDIM, big,
        NTOK, FFDIM, DMODEL, 1);
    gemm_kernel<128, 64><<<dim3(DMODEL / 64, NTOK / 128), 256, 0, stream>>>(
        big, w2 + (size_t)l * FFDIM * DMODEL, b2 + (size_t)l * DMODEL, h,
        NTOK, DMODEL, FFDIM, 2);
  }

  ln_kernel<<<NTOK, 256, 0, stream>>>(h, head_ln_g, head_ln_b, y);
  gemm_kernel<64, 64><<<dim3((DMODEL / 2) / 64, NTOK / 64), 256, 0, stream>>>(
      y, head_w1, head_b1, t1, NTOK, DMODEL / 2, DMODEL, 1);
  head_kernel<<<NTOK, 256, 0, stream>>>(h, t1, head_w2, head_b2,
                                        gate_w, gate_b, gatec_w, gatec_b,
                                        (float*)d_out);
}

// Round 4
// 1505.323 us; speedup vs baseline: 5.6011x; 3.0539x over previous
//
#include <hip/hip_runtime.h>
#include <math.h>

#define S_LEN 1024
#define DMODEL 1024
#define NHEAD 16
#define DHEAD 64
#define NLAYER 4
#define FFDIM 4096
#define WIN_HALF 128
#define LN_EPS 1e-5f

typedef unsigned short u16;
typedef __attribute__((ext_vector_type(8))) short bf16x8;
typedef __attribute__((ext_vector_type(4))) float f32x4;

__device__ __forceinline__ u16 f2bf(float f) {
  union { float f; unsigned u; } v; v.f = f;
  unsigned r = v.u + 0x7fffu + ((v.u >> 16) & 1u);
  return (u16)(r >> 16);
}
__device__ __forceinline__ float bf2f(u16 u) {
  union { unsigned u; float f; } v; v.u = ((unsigned)u) << 16;
  return v.f;
}
__device__ __forceinline__ float gelu_exact(float x) {
  return 0.5f * x * (1.0f + erff(x * 0.70710678118654752f));
}
__device__ __forceinline__ void gload_lds16(const void* g, void* l) {
  __builtin_amdgcn_global_load_lds(
      (const __attribute__((address_space(1))) unsigned int*)g,
      (__attribute__((address_space(3))) unsigned int*)l, 16, 0, 0);
}

// ---------------------------------------------------------------- LayerNorm (fp32 in, bf16 out)
__global__ __launch_bounds__(256) void ln_kernel(
    const float* __restrict__ x, const float* __restrict__ g,
    const float* __restrict__ b, u16* __restrict__ y) {
  __shared__ float red[8];
  const int row = blockIdx.x;
  const int t = threadIdx.x;
  float4 v = ((const float4*)(x + (size_t)row * DMODEL))[t];
  float s = v.x + v.y + v.z + v.w;
  float ss = v.x * v.x + v.y * v.y + v.z * v.z + v.w * v.w;
#pragma unroll
  for (int o = 32; o > 0; o >>= 1) {
    s += __shfl_down(s, o);
    ss += __shfl_down(ss, o);
  }
  const int wid = t >> 6;
  if ((t & 63) == 0) { red[wid] = s; red[4 + wid] = ss; }
  __syncthreads();
  if (t == 0) {
    float S1 = red[0] + red[1] + red[2] + red[3];
    float S2 = red[4] + red[5] + red[6] + red[7];
    float m = S1 * (1.0f / DMODEL);
    float var = S2 * (1.0f / DMODEL) - m * m;
    red[0] = m;
    red[1] = rsqrtf(var + LN_EPS);
  }
  __syncthreads();
  const float m = red[0], inv = red[1];
  float4 gv = ((const float4*)g)[t];
  float4 bv = ((const float4*)b)[t];
  ushort4 o4;
  o4.x = f2bf((v.x - m) * inv * gv.x + bv.x);
  o4.y = f2bf((v.y - m) * inv * gv.y + bv.y);
  o4.z = f2bf((v.z - m) * inv * gv.z + bv.z);
  o4.w = f2bf((v.w - m) * inv * gv.w + bv.w);
  *(ushort4*)(y + (size_t)row * DMODEL + t * 4) = o4;
}

// ---------------------------------------------------------------- transpose+cast: W[K][N] f32 -> Wt[N][K] bf16
__global__ __launch_bounds__(256) void transpose_cast(
    const float* __restrict__ W, u16* __restrict__ Wt, int K, int N) {
  __shared__ float t[32][33];
  const int nb = blockIdx.x * 32, kb = blockIdx.y * 32;
  const int tx = threadIdx.x & 31, ty = threadIdx.x >> 5;  // ty: 0..7
#pragma unroll
  for (int i = 0; i < 4; i++)
    t[ty + i * 8][tx] = W[(size_t)(kb + ty + i * 8) * N + nb + tx];
  __syncthreads();
#pragma unroll
  for (int i = 0; i < 4; i++)
    Wt[(size_t)(nb + ty + i * 8) * K + kb + tx] = f2bf(t[tx][ty + i * 8]);
}

// ---------------------------------------------------------------- bf16 MFMA GEMM
// C[M,N] = A[M,K](bf16) @ Bt[N,K]^T(bf16), fp32 accumulate.
// FLAGS: 1=bias, 2=gelu, 4=residual(+= into Cf fp32), 8=bf16 out (Cb)
// BM=128, BK=32, 256 threads = 4 waves.
template <int BN, int FLAGS>
__global__ __launch_bounds__(256) void mfma_gemm(
    const u16* __restrict__ A, const u16* __restrict__ Bt,
    const float* __restrict__ bias, u16* __restrict__ Cb,
    float* __restrict__ Cf, int M, int N, int K) {
  constexpr int WAVES_M = (BN == 128) ? 2 : 4;
  constexpr int WAVES_N = 4 / WAVES_M;
  constexpr int MF = 128 / (WAVES_M * 16);  // 4 (BN=128) or 2 (BN=64)
  constexpr int NF = BN / (WAVES_N * 16);   // 4
  __shared__ __align__(16) u16 As[128 * 32];
  __shared__ __align__(16) u16 Bs[BN * 32];

  const int tid = threadIdx.x;
  const int wid = tid >> 6, lane = tid & 63;
  const int wr = wid / WAVES_N, wc = wid % WAVES_N;
  const int row0 = blockIdx.y * 128, col0 = blockIdx.x * BN;

  const int frow = lane & 15, fk = (lane >> 4) * 8;
  const int lr = lane >> 2, lk8 = (lane & 3) * 8;

  f32x4 acc[MF][NF];
#pragma unroll
  for (int m = 0; m < MF; m++)
#pragma unroll
    for (int n = 0; n < NF; n++) acc[m][n] = (f32x4){0.f, 0.f, 0.f, 0.f};

  for (int kt = 0; kt < K; kt += 32) {
    __syncthreads();  // previous iter's LDS reads complete
#pragma unroll
    for (int i = 0; i < 2; i++) {
      const int seg = i * 4 + wid;
      const int r = seg * 16 + lr;
      gload_lds16(A + (size_t)(row0 + r) * K + kt + lk8, (void*)(As + seg * 512));
    }
#pragma unroll
    for (int i = 0; i < BN / 64; i++) {
      const int seg = i * 4 + wid;
      const int r = seg * 16 + lr;
      gload_lds16(Bt + (size_t)(col0 + r) * K + kt + lk8, (void*)(Bs + seg * 512));
    }
    __syncthreads();  // drains vmcnt + lgkmcnt

    bf16x8 af[MF], bfr[NF];
#pragma unroll
    for (int m = 0; m < MF; m++)
      af[m] = *(const bf16x8*)(As + (wr * MF * 16 + m * 16 + frow) * 32 + fk);
#pragma unroll
    for (int n = 0; n < NF; n++)
      bfr[n] = *(const bf16x8*)(Bs + (wc * NF * 16 + n * 16 + frow) * 32 + fk);
#pragma unroll
    for (int m = 0; m < MF; m++)
#pragma unroll
      for (int n = 0; n < NF; n++)
        acc[m][n] = __builtin_amdgcn_mfma_f32_16x16x32_bf16(af[m], bfr[n], acc[m][n], 0, 0, 0);
  }

  // epilogue: C layout col=lane&15, row=(lane>>4)*4+j  [m89-verified]
  const int crow0 = row0 + wr * (MF * 16);
  const int ccol0 = col0 + wc * (NF * 16);
#pragma unroll
  for (int m = 0; m < MF; m++) {
#pragma unroll
    for (int n = 0; n < NF; n++) {
      const int col = ccol0 + n * 16 + (lane & 15);
      const float bv = (FLAGS & 1) ? bias[col] : 0.f;
#pragma unroll
      for (int j = 0; j < 4; j++) {
        const int row = crow0 + m * 16 + (lane >> 4) * 4 + j;
        float e = acc[m][n][j] + bv;
        if (FLAGS & 2) e = gelu_exact(e);
        if (FLAGS & 4) {
          float* p = Cf + (size_t)row * N + col;
          *p += e;
        } else if (FLAGS & 8) {
          Cb[(size_t)row * N + col] = f2bf(e);
        } else {
          Cf[(size_t)row * N + col] = e;
        }
      }
    }
  }
}

// ---------------------------------------------------------------- Flash attention (bf16 qkv in, bf16 out, fp32 math)
__global__ __launch_bounds__(256) void fattn_kernel(
    const u16* __restrict__ qkv, const float* __restrict__ bias,
    u16* __restrict__ out, int use_window) {
  __shared__ float Qs[64][68];
  __shared__ float KVs[64][68];
  __shared__ float Ps[64][67];

  const int b = blockIdx.z, h = blockIdx.y;
  const int qt = (b == 0) ? blockIdx.x : ((int)gridDim.x - 1 - (int)blockIdx.x);
  const int q0 = qt << 6;
  const int tid = threadIdx.x;
  const int tx = tid & 15, ty = tid >> 4;

  const u16* qbase = qkv + (size_t)b * S_LEN * (3 * DMODEL) + h * DHEAD;
  const u16* kbase = qbase + DMODEL;
  const u16* vbase = qbase + 2 * DMODEL;
  const float* bbase = bias + (size_t)(b * NHEAD + h) * S_LEN * S_LEN;

#pragma unroll
  for (int p = 0; p < 4; p++) {
    const int idx = tid + p * 256;
    const int row = idx >> 4, c4 = (idx & 15) * 4;
    ushort4 v4 = *(const ushort4*)(qbase + (size_t)(q0 + row) * (3 * DMODEL) + c4);
    Qs[c4 + 0][row] = bf2f(v4.x); Qs[c4 + 1][row] = bf2f(v4.y);
    Qs[c4 + 2][row] = bf2f(v4.z); Qs[c4 + 3][row] = bf2f(v4.w);
  }

  float O[4][4] = {};
  float mr[4] = {-1e30f, -1e30f, -1e30f, -1e30f};
  float lrr[4] = {0.f, 0.f, 0.f, 0.f};

  const int lo_t = use_window ? (max(0, q0 - WIN_HALF) >> 6) : 0;
  const int hi_t = q0 >> 6;

  for (int kt = lo_t; kt <= hi_t; kt++) {
    const int k0 = kt << 6;
    __syncthreads();
#pragma unroll
    for (int p = 0; p < 4; p++) {
      const int idx = tid + p * 256;
      const int row = idx >> 4, c4 = (idx & 15) * 4;
      ushort4 v4 = *(const ushort4*)(kbase + (size_t)(k0 + row) * (3 * DMODEL) + c4);
      KVs[c4 + 0][row] = bf2f(v4.x); KVs[c4 + 1][row] = bf2f(v4.y);
      KVs[c4 + 2][row] = bf2f(v4.z); KVs[c4 + 3][row] = bf2f(v4.w);
    }
    __syncthreads();

    float acc[4][4] = {};
#pragma unroll 16
    for (int dd = 0; dd < 64; dd++) {
      float4 a = *(const float4*)&Qs[dd][ty * 4];
      float4 kv = *(const float4*)&KVs[dd][tx * 4];
      acc[0][0] += a.x * kv.x; acc[0][1] += a.x * kv.y; acc[0][2] += a.x * kv.z; acc[0][3] += a.x * kv.w;
      acc[1][0] += a.y * kv.x; acc[1][1] += a.y * kv.y; acc[1][2] += a.y * kv.z; acc[1][3] += a.y * kv.w;
      acc[2][0] += a.z * kv.x; acc[2][1] += a.z * kv.y; acc[2][2] += a.z * kv.z; acc[2][3] += a.z * kv.w;
      acc[3][0] += a.w * kv.x; acc[3][1] += a.w * kv.y; acc[3][2] += a.w * kv.z; acc[3][3] += a.w * kv.w;
    }

#pragma unroll
    for (int r = 0; r < 4; r++) {
      const int q = q0 + ty * 4 + r;
      float4 bb = *(const float4*)(bbase + (size_t)q * S_LEN + k0 + tx * 4);
      float s0 = acc[r][0] * 0.125f + bb.x;
      float s1 = acc[r][1] * 0.125f + bb.y;
      float s2 = acc[r][2] * 0.125f + bb.z;
      float s3 = acc[r][3] * 0.125f + bb.w;
      const int kb = k0 + tx * 4;
      if (kb + 0 > q || (use_window && q - (kb + 0) > WIN_HALF)) s0 = -1e30f;
      if (kb + 1 > q || (use_window && q - (kb + 1) > WIN_HALF)) s1 = -1e30f;
      if (kb + 2 > q || (use_window && q - (kb + 2) > WIN_HALF)) s2 = -1e30f;
      if (kb + 3 > q || (use_window && q - (kb + 3) > WIN_HALF)) s3 = -1e30f;

      float pm = fmaxf(fmaxf(s0, s1), fmaxf(s2, s3));
      pm = fmaxf(pm, __shfl_xor(pm, 1));
      pm = fmaxf(pm, __shfl_xor(pm, 2));
      pm = fmaxf(pm, __shfl_xor(pm, 4));
      pm = fmaxf(pm, __shfl_xor(pm, 8));
      const float mnew = fmaxf(mr[r], pm);
      const float alpha = __expf(mr[r] - mnew);
      mr[r] = mnew;
      const float p0 = __expf(s0 - mnew);
      const float p1 = __expf(s1 - mnew);
      const float p2 = __expf(s2 - mnew);
      const float p3 = __expf(s3 - mnew);
      float ps = p0 + p1 + p2 + p3;
      ps += __shfl_xor(ps, 1);
      ps += __shfl_xor(ps, 2);
      ps += __shfl_xor(ps, 4);
      ps += __shfl_xor(ps, 8);
      lrr[r] = lrr[r] * alpha + ps;
      O[r][0] *= alpha; O[r][1] *= alpha; O[r][2] *= alpha; O[r][3] *= alpha;
      const int qc = ty * 4 + r;
      Ps[tx * 4 + 0][qc] = p0;
      Ps[tx * 4 + 1][qc] = p1;
      Ps[tx * 4 + 2][qc] = p2;
      Ps[tx * 4 + 3][qc] = p3;
    }
    __syncthreads();

#pragma unroll
    for (int p = 0; p < 4; p++) {
      const int idx = tid + p * 256;
      const int row = idx >> 4, c4 = (idx & 15) * 4;
      ushort4 v4 = *(const ushort4*)(vbase + (size_t)(k0 + row) * (3 * DMODEL) + c4);
      KVs[row][c4 + 0] = bf2f(v4.x); KVs[row][c4 + 1] = bf2f(v4.y);
      KVs[row][c4 + 2] = bf2f(v4.z); KVs[row][c4 + 3] = bf2f(v4.w);
    }
    __syncthreads();

#pragma unroll 16
    for (int kk = 0; kk < 64; kk++) {
      const float p0 = Ps[kk][ty * 4 + 0];
      const float p1 = Ps[kk][ty * 4 + 1];
      const float p2 = Ps[kk][ty * 4 + 2];
      const float p3 = Ps[kk][ty * 4 + 3];
      float4 vv = *(const float4*)&KVs[kk][tx * 4];
      O[0][0] += p0 * vv.x; O[0][1] += p0 * vv.y; O[0][2] += p0 * vv.z; O[0][3] += p0 * vv.w;
      O[1][0] += p1 * vv.x; O[1][1] += p1 * vv.y; O[1][2] += p1 * vv.z; O[1][3] += p1 * vv.w;
      O[2][0] += p2 * vv.x; O[2][1] += p2 * vv.y; O[2][2] += p2 * vv.z; O[2][3] += p2 * vv.w;
      O[3][0] += p3 * vv.x; O[3][1] += p3 * vv.y; O[3][2] += p3 * vv.z; O[3][3] += p3 * vv.w;
    }
  }

#pragma unroll
  for (int r = 0; r < 4; r++) {
    const float inv = 1.0f / lrr[r];
    ushort4 o4;
    o4.x = f2bf(O[r][0] * inv); o4.y = f2bf(O[r][1] * inv);
    o4.z = f2bf(O[r][2] * inv); o4.w = f2bf(O[r][3] * inv);
    *(ushort4*)(out + (size_t)(b * S_LEN + q0 + ty * 4 + r) * DMODEL + h * DHEAD + tx * 4) = o4;
  }
}

// ---------------------------------------------------------------- Head + gate
__global__ __launch_bounds__(256) void head_kernel(
    const float* __restrict__ h, const u16* __restrict__ t1,
    const float* __restrict__ w2, const float* __restrict__ b2,
    const float* __restrict__ gate_w, const float* __restrict__ gate_b,
    const float* __restrict__ gatec_w, const float* __restrict__ gatec_b,
    float* __restrict__ out) {
  __shared__ float redm[4][8];
  const int row = blockIdx.x;
  const int t = threadIdx.x;
  const float* hrow = h + (size_t)row * DMODEL;
  const u16* trow = t1 + (size_t)row * (DMODEL / 2);

  float p[8] = {0, 0, 0, 0, 0, 0, 0, 0};
  for (int i = t; i < DMODEL / 2; i += 256) {
    float tv = bf2f(trow[i]);
#pragma unroll
    for (int j = 0; j < 7; j++) p[j] += tv * w2[i * 7 + j];
  }
  for (int i = t; i < DMODEL; i += 256) p[7] += hrow[i] * gate_w[i];

#pragma unroll
  for (int j = 0; j < 8; j++) {
#pragma unroll
    for (int o = 32; o > 0; o >>= 1) p[j] += __shfl_down(p[j], o);
  }
  const int wid = t >> 6;
  if ((t & 63) == 0) {
#pragma unroll
    for (int j = 0; j < 8; j++) redm[wid][j] = p[j];
  }
  __syncthreads();

  float raw[7], gd = 0.f;
#pragma unroll
  for (int j = 0; j < 7; j++)
    raw[j] = redm[0][j] + redm[1][j] + redm[2][j] + redm[3][j] + b2[j];
  gd = redm[0][7] + redm[1][7] + redm[2][7] + redm[3][7] + gate_b[0];

  float sig[7];
#pragma unroll
  for (int j = 0; j < 7; j++) sig[j] = 1.0f / (1.0f + __expf(-raw[j]));
  const float learned = 1.0f / (1.0f + __expf(-gd));
  const float s2v = tanhf(raw[2]) * 2.0f;
  const float gate =
      1.0f / (1.0f + __expf(-(learned * gatec_w[0] + sig[0] * gatec_w[1] + gatec_b[0])));

  float* orow = out + (size_t)row * (DMODEL + 8);
  float4 hv = ((const float4*)hrow)[t];
  *(float4*)(orow + t * 4) = hv;
  if (t == 0) {
    orow[DMODEL + 0] = sig[0];
    orow[DMODEL + 1] = sig[1];
    orow[DMODEL + 2] = s2v;
    orow[DMODEL + 3] = sig[3];
    orow[DMODEL + 4] = sig[4];
    orow[DMODEL + 5] = sig[5];
    orow[DMODEL + 6] = sig[6];
    orow[DMODEL + 7] = gate;
  }
}

// ---------------------------------------------------------------- launch
extern "C" void kernel_launch(void* const* d_in, const int* in_sizes, int n_in,
                              void* d_out, int out_size, void* d_ws, size_t ws_size,
                              hipStream_t stream) {
  const float* x = (const float*)d_in[0];
  const float* tb = (const float*)d_in[1];
  const float* qkv_w = (const float*)d_in[2];
  const float* out_w = (const float*)d_in[3];
  const float* w1 = (const float*)d_in[4];
  const float* b1 = (const float*)d_in[5];
  const float* w2 = (const float*)d_in[6];
  const float* b2 = (const float*)d_in[7];
  const float* ln1_g = (const float*)d_in[8];
  const float* ln1_b = (const float*)d_in[9];
  const float* ln2_g = (const float*)d_in[10];
  const float* ln2_b = (const float*)d_in[11];
  const float* head_ln_g = (const float*)d_in[12];
  const float* head_ln_b = (const float*)d_in[13];
  const float* head_w1 = (const float*)d_in[14];
  const float* head_b1 = (const float*)d_in[15];
  const float* head_w2 = (const float*)d_in[16];
  const float* head_b2 = (const float*)d_in[17];
  const float* gate_w = (const float*)d_in[18];
  const float* gate_b = (const float*)d_in[19];
  const float* gatec_w = (const float*)d_in[20];
  const float* gatec_b = (const float*)d_in[21];

  const size_t NTOK = 2 * S_LEN;
  const size_t SZ_BSD = NTOK * DMODEL;

  // workspace layout (bytes, 16-aligned):
  char* ws = (char*)d_ws;
  float* h = (float*)ws;                       ws += SZ_BSD * 4;          // 8.4 MB
  u16* y = (u16*)ws;                           ws += SZ_BSD * 2;          // 4.2 MB
  u16* attno = (u16*)ws;                       ws += SZ_BSD * 2;          // 4.2 MB
  u16* big = (u16*)ws;                         ws += NTOK * FFDIM * 2;    // 16.8 MB (qkv 12.6MB / ffn1)
  u16* t1 = (u16*)ws;                          ws += NTOK * (DMODEL / 2) * 2;  // 2.1 MB
  u16* wqkv_t = (u16*)ws;                      ws += (size_t)3 * DMODEL * DMODEL * 2;
  u16* wout_t = (u16*)ws;                      ws += (size_t)DMODEL * DMODEL * 2;
  u16* w1_t = (u16*)ws;                        ws += (size_t)DMODEL * FFDIM * 2;
  u16* w2_t = (u16*)ws;                        ws += (size_t)DMODEL * FFDIM * 2;
  u16* hw1_t = (u16*)ws;                       ws += (size_t)DMODEL * (DMODEL / 2) * 2;

  hipMemcpyAsync(h, x, SZ_BSD * sizeof(float), hipMemcpyDeviceToDevice, stream);

  for (int l = 0; l < NLAYER; l++) {
    // per-layer weight transposes (stream-serial; buffer reused next layer)
    transpose_cast<<<dim3(3 * DMODEL / 32, DMODEL / 32), 256, 0, stream>>>(
        qkv_w + (size_t)l * DMODEL * 3 * DMODEL, wqkv_t, DMODEL, 3 * DMODEL);
    transpose_cast<<<dim3(DMODEL / 32, DMODEL / 32), 256, 0, stream>>>(
        out_w + (size_t)l * DMODEL * DMODEL, wout_t, DMODEL, DMODEL);
    transpose_cast<<<dim3(FFDIM / 32, DMODEL / 32), 256, 0, stream>>>(
        w1 + (size_t)l * DMODEL * FFDIM, w1_t, DMODEL, FFDIM);
    transpose_cast<<<dim3(DMODEL / 32, FFDIM / 32), 256, 0, stream>>>(
        w2 + (size_t)l * FFDIM * DMODEL, w2_t, FFDIM, DMODEL);

    ln_kernel<<<NTOK, 256, 0, stream>>>(h, ln1_g + l * DMODEL, ln1_b + l * DMODEL, y);
    mfma_gemm<128, 8><<<dim3(3 * DMODEL / 128, NTOK / 128), 256, 0, stream>>>(
        y, wqkv_t, nullptr, big, nullptr, NTOK, 3 * DMODEL, DMODEL);
    fattn_kernel<<<dim3(S_LEN / 64, NHEAD, 2), 256, 0, stream>>>(
        big, tb, attno, (l % 2 == 0) ? 1 : 0);
    mfma_gemm<64, 4><<<dim3(DMODEL / 64, NTOK / 128), 256, 0, stream>>>(
        attno, wout_t, nullptr, nullptr, h, NTOK, DMODEL, DMODEL);
    ln_kernel<<<NTOK, 256, 0, stream>>>(h, ln2_g + l * DMODEL, ln2_b + l * DMODEL, y);
    mfma_gemm<128, 1 | 2 | 8><<<dim3(FFDIM / 128, NTOK / 128), 256, 0, stream>>>(
        y, w1_t, b1 + (size_t)l * FFDIM, big, nullptr, NTOK, FFDIM, DMODEL);
    mfma_gemm<64, 1 | 4><<<dim3(DMODEL / 64, NTOK / 128), 256, 0, stream>>>(
        big, w2_t, b2 + (size_t)l * DMODEL, nullptr, h, NTOK, DMODEL, FFDIM);
  }

  transpose_cast<<<dim3((DMODEL / 2) / 32, DMODEL / 32), 256, 0, stream>>>(
      head_w1, hw1_t, DMODEL, DMODEL / 2);
  ln_kernel<<<NTOK, 256, 0, stream>>>(h, head_ln_g, head_ln_b, y);
  mfma_gemm<64, 1 | 2 | 8><<<dim3((DMODEL / 2) / 64, NTOK / 128), 256, 0, stream>>>(
      y, hw1_t, head_b1, t1, nullptr, NTOK, DMODEL / 2, DMODEL);
  head_kernel<<<NTOK, 256, 0, stream>>>(h, t1, head_w2, head_b2,
                                        gate_w, gate_b, gatec_w, gatec_b,
                                        (float*)d_out);
}

// Round 8
// 1264.886 us; speedup vs baseline: 6.6658x; 1.1901x over previous
//
#include <hip/hip_runtime.h>
#include <math.h>

#define S_LEN 1024
#define DMODEL 1024
#define NHEAD 16
#define DHEAD 64
#define NLAYER 4
#define FFDIM 4096
#define WIN_HALF 128
#define LN_EPS 1e-5f

typedef unsigned short u16;
typedef __attribute__((ext_vector_type(8))) short short8;
typedef __attribute__((ext_vector_type(4))) float f32x4;

__device__ __forceinline__ u16 f2bf(float f) {
  union { float f; unsigned u; } v; v.f = f;
  unsigned r = v.u + 0x7fffu + ((v.u >> 16) & 1u);
  return (u16)(r >> 16);
}
__device__ __forceinline__ float bf2f(u16 u) {
  union { unsigned u; float f; } v; v.u = ((unsigned)u) << 16;
  return v.f;
}
__device__ __forceinline__ float gelu_exact(float x) {
  return 0.5f * x * (1.0f + erff(x * 0.70710678118654752f));
}
__device__ __forceinline__ void gload_lds16(const void* g, void* l) {
  __builtin_amdgcn_global_load_lds(
      (const __attribute__((address_space(1))) unsigned int*)g,
      (__attribute__((address_space(3))) unsigned int*)l, 16, 0, 0);
}

// ---------------------------------------------------------------- LayerNorm (fp32 in, bf16 out)
__global__ __launch_bounds__(256) void ln_kernel(
    const float* __restrict__ x, const float* __restrict__ g,
    const float* __restrict__ b, u16* __restrict__ y) {
  __shared__ float red[8];
  const int row = blockIdx.x;
  const int t = threadIdx.x;
  float4 v = ((const float4*)(x + (size_t)row * DMODEL))[t];
  float s = v.x + v.y + v.z + v.w;
  float ss = v.x * v.x + v.y * v.y + v.z * v.z + v.w * v.w;
#pragma unroll
  for (int o = 32; o > 0; o >>= 1) {
    s += __shfl_down(s, o);
    ss += __shfl_down(ss, o);
  }
  const int wid = t >> 6;
  if ((t & 63) == 0) { red[wid] = s; red[4 + wid] = ss; }
  __syncthreads();
  if (t == 0) {
    float S1 = red[0] + red[1] + red[2] + red[3];
    float S2 = red[4] + red[5] + red[6] + red[7];
    float m = S1 * (1.0f / DMODEL);
    float var = S2 * (1.0f / DMODEL) - m * m;
    red[0] = m;
    red[1] = rsqrtf(var + LN_EPS);
  }
  __syncthreads();
  const float m = red[0], inv = red[1];
  float4 gv = ((const float4*)g)[t];
  float4 bv = ((const float4*)b)[t];
  ushort4 o4;
  o4.x = f2bf((v.x - m) * inv * gv.x + bv.x);
  o4.y = f2bf((v.y - m) * inv * gv.y + bv.y);
  o4.z = f2bf((v.z - m) * inv * gv.z + bv.z);
  o4.w = f2bf((v.w - m) * inv * gv.w + bv.w);
  *(ushort4*)(y + (size_t)row * DMODEL + t * 4) = o4;
}

// ---------------------------------------------------------------- transpose+cast: W[K][N] f32 -> Wt[N][K] bf16
__global__ __launch_bounds__(256) void transpose_cast(
    const float* __restrict__ W, u16* __restrict__ Wt, int K, int N) {
  __shared__ float t[32][33];
  const int nb = blockIdx.x * 32, kb = blockIdx.y * 32;
  const int tx = threadIdx.x & 31, ty = threadIdx.x >> 5;
#pragma unroll
  for (int i = 0; i < 4; i++)
    t[ty + i * 8][tx] = W[(size_t)(kb + ty + i * 8) * N + nb + tx];
  __syncthreads();
#pragma unroll
  for (int i = 0; i < 4; i++)
    Wt[(size_t)(nb + ty + i * 8) * K + kb + tx] = f2bf(t[tx][ty + i * 8]);
}

// ---------------------------------------------------------------- bf16 MFMA GEMM
// C[M,N] = A[M,K](bf16) @ Bt[N,K]^T(bf16), fp32 accumulate.
// FLAGS: 1=bias, 2=gelu, 4=residual(+= into Cf fp32), 8=bf16 out (Cb)
// KS>1: split-K via atomicAdd into Cf (requires FLAGS&4 semantics, no gelu/bf16)
template <int BN, int FLAGS, int KS>
__global__ __launch_bounds__(256) void mfma_gemm(
    const u16* __restrict__ A, const u16* __restrict__ Bt,
    const float* __restrict__ bias, u16* __restrict__ Cb,
    float* __restrict__ Cf, int M, int N, int K) {
  constexpr int WAVES_M = (BN == 128) ? 2 : 4;
  constexpr int WAVES_N = 4 / WAVES_M;
  constexpr int MF = 128 / (WAVES_M * 16);
  constexpr int NF = BN / (WAVES_N * 16);
  __shared__ __align__(16) u16 As[128 * 32];
  __shared__ __align__(16) u16 Bs[BN * 32];

  const int tid = threadIdx.x;
  const int wid = tid >> 6, lane = tid & 63;
  const int wr = wid / WAVES_N, wc = wid % WAVES_N;
  const int row0 = blockIdx.y * 128, col0 = blockIdx.x * BN;
  const int kz = blockIdx.z;
  const int kbeg = kz * (K / KS), kend = kbeg + K / KS;

  const int frow = lane & 15, fk = (lane >> 4) * 8;
  const int lr = lane >> 2, lk8 = (lane & 3) * 8;

  f32x4 acc[MF][NF];
#pragma unroll
  for (int m = 0; m < MF; m++)
#pragma unroll
    for (int n = 0; n < NF; n++) acc[m][n] = (f32x4){0.f, 0.f, 0.f, 0.f};

  for (int kt = kbeg; kt < kend; kt += 32) {
    __syncthreads();
#pragma unroll
    for (int i = 0; i < 2; i++) {
      const int seg = i * 4 + wid;
      const int r = seg * 16 + lr;
      gload_lds16(A + (size_t)(row0 + r) * K + kt + lk8, (void*)(As + seg * 512));
    }
#pragma unroll
    for (int i = 0; i < BN / 64; i++) {
      const int seg = i * 4 + wid;
      const int r = seg * 16 + lr;
      gload_lds16(Bt + (size_t)(col0 + r) * K + kt + lk8, (void*)(Bs + seg * 512));
    }
    __syncthreads();

    short8 af[MF], bfr[NF];
#pragma unroll
    for (int m = 0; m < MF; m++)
      af[m] = *(const short8*)(As + (wr * MF * 16 + m * 16 + frow) * 32 + fk);
#pragma unroll
    for (int n = 0; n < NF; n++)
      bfr[n] = *(const short8*)(Bs + (wc * NF * 16 + n * 16 + frow) * 32 + fk);
#pragma unroll
    for (int m = 0; m < MF; m++)
#pragma unroll
      for (int n = 0; n < NF; n++)
        acc[m][n] = __builtin_amdgcn_mfma_f32_16x16x32_bf16(af[m], bfr[n], acc[m][n], 0, 0, 0);
  }

  const int crow0 = row0 + wr * (MF * 16);
  const int ccol0 = col0 + wc * (NF * 16);
#pragma unroll
  for (int m = 0; m < MF; m++) {
#pragma unroll
    for (int n = 0; n < NF; n++) {
      const int col = ccol0 + n * 16 + (lane & 15);
      const float bv = ((FLAGS & 1) && (KS == 1 || kz == 0)) ? bias[col] : 0.f;
#pragma unroll
      for (int j = 0; j < 4; j++) {
        const int row = crow0 + m * 16 + (lane >> 4) * 4 + j;
        float e = acc[m][n][j] + bv;
        if (FLAGS & 2) e = gelu_exact(e);
        if (KS > 1) {
          atomicAdd(Cf + (size_t)row * N + col, e);
        } else if (FLAGS & 4) {
          float* p = Cf + (size_t)row * N + col;
          *p += e;
        } else if (FLAGS & 8) {
          Cb[(size_t)row * N + col] = f2bf(e);
        } else {
          Cf[(size_t)row * N + col] = e;
        }
      }
    }
  }
}

// ---------------------------------------------------------------- MFMA flash attention
// Block = (64 q, head, batch), 4 waves x 16 q-rows. QK^T and PV on matrix cores.
// LDS XOR-swizzled (16B slot ^= row&7) so all b128 frag reads hit the 8-cycle floor.
__global__ __launch_bounds__(256) void fattn_kernel(
    const u16* __restrict__ qkv, const float* __restrict__ bias,
    u16* __restrict__ out, int use_window) {
  __shared__ __align__(16) u16 Kl[64 * 64];      // [key][d], swizzled
  __shared__ __align__(16) u16 Vt[64 * 64];      // [d][key], swizzled
  __shared__ __align__(16) u16 Pl[4][16 * 64];   // per-wave [q][k], swizzled

  const int b = blockIdx.z, h = blockIdx.y;
  // heavy/light pairing: each CU gets one b=0 and one b=1 block summing to 17 tiles
  const int qt = (b == 0) ? blockIdx.x : ((int)gridDim.x - 1 - (int)blockIdx.x);
  const int q0 = qt << 6;
  const int tid = threadIdx.x;
  const int wid = tid >> 6, l = tid & 63;
  const int lg = l >> 4, l15 = l & 15, l7 = l & 7;

  const u16* qbase = qkv + (size_t)b * S_LEN * (3 * DMODEL) + h * DHEAD;
  const u16* kbase = qbase + DMODEL;
  const u16* vbase = qbase + 2 * DMODEL;
  const float* bbase = bias + (size_t)(b * NHEAD + h) * S_LEN * S_LEN;

  const int qw = q0 + wid * 16;

  short8 aQ[2];
#pragma unroll
  for (int ds = 0; ds < 2; ds++)
    aQ[ds] = *(const short8*)(qbase + (size_t)(qw + l15) * (3 * DMODEL) + ds * 32 + lg * 8);

  f32x4 o[4];
#pragma unroll
  for (int dt = 0; dt < 4; dt++) o[dt] = (f32x4){0.f, 0.f, 0.f, 0.f};
  float mr[4] = {-1e30f, -1e30f, -1e30f, -1e30f};
  float lrw[4] = {0.f, 0.f, 0.f, 0.f};

  // staging thread-constants
  const int kk1 = tid >> 3, ks1 = tid & 7;         // K chunks tid, tid+256
  const int kk2 = (tid + 256) >> 3;
  const int vk = tid >> 2, vc1 = tid & 3;          // V row, chunk pair

  const int lo_t = use_window ? max(0, qt - 2) : 0;
  const int hi_t = qt;

  for (int kt = lo_t; kt <= hi_t; kt++) {
    const int k0 = kt << 6;
    __syncthreads();  // previous tile's frag reads done
    {  // K: [key][d] with 16B-slot swizzle
      short8 g1 = *(const short8*)(kbase + (size_t)(k0 + kk1) * (3 * DMODEL) + ks1 * 8);
      short8 g2 = *(const short8*)(kbase + (size_t)(k0 + kk2) * (3 * DMODEL) + ks1 * 8);
      ((short8*)Kl)[kk1 * 8 + (ks1 ^ (kk1 & 7))] = g1;
      ((short8*)Kl)[kk2 * 8 + (ks1 ^ (kk2 & 7))] = g2;
    }
    {  // V transposed: Vt[d][k], swizzle slot ^= (d>>3)
      short8 g1 = *(const short8*)(vbase + (size_t)(k0 + vk) * (3 * DMODEL) + vc1 * 8);
      short8 g2 = *(const short8*)(vbase + (size_t)(k0 + vk) * (3 * DMODEL) + (vc1 + 4) * 8);
#pragma unroll
      for (int i = 0; i < 8; i++) {
        const int d1 = vc1 * 8 + i, d2 = d1 + 32;
        Vt[d1 * 64 + (vk ^ ((d1 >> 3) << 3))] = (u16)(unsigned short)g1[i];
        Vt[d2 * 64 + (vk ^ ((d2 >> 3) << 3))] = (u16)(unsigned short)g2[i];
      }
    }
    __syncthreads();

    // S = Q K^T  (C: row q = lg*4+j, col k = n*16+l15)
    f32x4 s[4];
#pragma unroll
    for (int n = 0; n < 4; n++) s[n] = (f32x4){0.f, 0.f, 0.f, 0.f};
#pragma unroll
    for (int ds = 0; ds < 2; ds++) {
#pragma unroll
      for (int n = 0; n < 4; n++) {
        const int key = n * 16 + l15;
        short8 bK = ((const short8*)Kl)[key * 8 + ((ds * 4 + lg) ^ l7)];
        s[n] = __builtin_amdgcn_mfma_f32_16x16x32_bf16(aQ[ds], bK, s[n], 0, 0, 0);
      }
    }

    // bias + mask + online softmax; P -> bf16 in per-wave LDS
#pragma unroll
    for (int j = 0; j < 4; j++) {
      const int q = qw + lg * 4 + j;
      const float* br = bbase + (size_t)q * S_LEN + k0 + l15;
      float sv[4];
#pragma unroll
      for (int n = 0; n < 4; n++) {
        const int k = k0 + n * 16 + l15;
        const float x = s[n][j] * 0.125f + br[n * 16];
        const bool valid = (k <= q) && (!use_window || (q - k) <= WIN_HALF);
        sv[n] = valid ? x : -1e30f;
      }
      float pm = fmaxf(fmaxf(sv[0], sv[1]), fmaxf(sv[2], sv[3]));
      pm = fmaxf(pm, __shfl_xor(pm, 1));
      pm = fmaxf(pm, __shfl_xor(pm, 2));
      pm = fmaxf(pm, __shfl_xor(pm, 4));
      pm = fmaxf(pm, __shfl_xor(pm, 8));
      const float mnew = fmaxf(mr[j], pm);
      const float alpha = __expf(mr[j] - mnew);
      mr[j] = mnew;
      const int qloc = lg * 4 + j;
      float ps = 0.f;
#pragma unroll
      for (int n = 0; n < 4; n++) {
        const float p = __expf(sv[n] - mnew);
        ps += p;
        Pl[wid][qloc * 64 + ((n * 16 + l15) ^ ((qloc & 7) << 3))] = f2bf(p);
      }
      ps += __shfl_xor(ps, 1);
      ps += __shfl_xor(ps, 2);
      ps += __shfl_xor(ps, 4);
      ps += __shfl_xor(ps, 8);
      lrw[j] = lrw[j] * alpha + ps;
#pragma unroll
      for (int dt = 0; dt < 4; dt++) o[dt][j] *= alpha;
    }

    // cross-lane P handoff through LDS within the wave
    asm volatile("s_waitcnt lgkmcnt(0)" ::: "memory");
    __builtin_amdgcn_sched_barrier(0);

    // O += P V  (A rows = q, B rows = d)
#pragma unroll
    for (int ks = 0; ks < 2; ks++) {
      short8 aP = ((const short8*)Pl[wid])[l15 * 8 + ((ks * 4 + lg) ^ l7)];
#pragma unroll
      for (int dt = 0; dt < 4; dt++) {
        const int d = dt * 16 + l15;
        short8 bV = ((const short8*)Vt)[d * 8 + ((ks * 4 + lg) ^ (d >> 3))];
        o[dt] = __builtin_amdgcn_mfma_f32_16x16x32_bf16(aP, bV, o[dt], 0, 0, 0);
      }
    }
  }

#pragma unroll
  for (int j = 0; j < 4; j++) {
    const float inv = 1.0f / lrw[j];
    const int q = qw + lg * 4 + j;
    u16* orow = out + (size_t)(b * S_LEN + q) * DMODEL + h * DHEAD;
#pragma unroll
    for (int dt = 0; dt < 4; dt++) orow[dt * 16 + l15] = f2bf(o[dt][j] * inv);
  }
}

// ---------------------------------------------------------------- Head + gate
__global__ __launch_bounds__(256) void head_kernel(
    const float* __restrict__ h, const u16* __restrict__ t1,
    const float* __restrict__ w2, const float* __restrict__ b2,
    const float* __restrict__ gate_w, const float* __restrict__ gate_b,
    const float* __restrict__ gatec_w, const float* __restrict__ gatec_b,
    float* __restrict__ out) {
  __shared__ float redm[4][8];
  const int row = blockIdx.x;
  const int t = threadIdx.x;
  const float* hrow = h + (size_t)row * DMODEL;
  const u16* trow = t1 + (size_t)row * (DMODEL / 2);

  float p[8] = {0, 0, 0, 0, 0, 0, 0, 0};
  for (int i = t; i < DMODEL / 2; i += 256) {
    float tv = bf2f(trow[i]);
#pragma unroll
    for (int j = 0; j < 7; j++) p[j] += tv * w2[i * 7 + j];
  }
  for (int i = t; i < DMODEL; i += 256) p[7] += hrow[i] * gate_w[i];

#pragma unroll
  for (int j = 0; j < 8; j++) {
#pragma unroll
    for (int o = 32; o > 0; o >>= 1) p[j] += __shfl_down(p[j], o);
  }
  const int wid = t >> 6;
  if ((t & 63) == 0) {
#pragma unroll
    for (int j = 0; j < 8; j++) redm[wid][j] = p[j];
  }
  __syncthreads();

  float raw[7], gd = 0.f;
#pragma unroll
  for (int j = 0; j < 7; j++)
    raw[j] = redm[0][j] + redm[1][j] + redm[2][j] + redm[3][j] + b2[j];
  gd = redm[0][7] + redm[1][7] + redm[2][7] + redm[3][7] + gate_b[0];

  float sig[7];
#pragma unroll
  for (int j = 0; j < 7; j++) sig[j] = 1.0f / (1.0f + __expf(-raw[j]));
  const float learned = 1.0f / (1.0f + __expf(-gd));
  const float s2v = tanhf(raw[2]) * 2.0f;
  const float gate =
      1.0f / (1.0f + __expf(-(learned * gatec_w[0] + sig[0] * gatec_w[1] + gatec_b[0])));

  float* orow = out + (size_t)row * (DMODEL + 8);
  float4 hv = ((const float4*)hrow)[t];
  *(float4*)(orow + t * 4) = hv;
  if (t == 0) {
    orow[DMODEL + 0] = sig[0];
    orow[DMODEL + 1] = sig[1];
    orow[DMODEL + 2] = s2v;
    orow[DMODEL + 3] = sig[3];
    orow[DMODEL + 4] = sig[4];
    orow[DMODEL + 5] = sig[5];
    orow[DMODEL + 6] = sig[6];
    orow[DMODEL + 7] = gate;
  }
}

// ---------------------------------------------------------------- launch
extern "C" void kernel_launch(void* const* d_in, const int* in_sizes, int n_in,
                              void* d_out, int out_size, void* d_ws, size_t ws_size,
                              hipStream_t stream) {
  const float* x = (const float*)d_in[0];
  const float* tb = (const float*)d_in[1];
  const float* qkv_w = (const float*)d_in[2];
  const float* out_w = (const float*)d_in[3];
  const float* w1 = (const float*)d_in[4];
  const float* b1 = (const float*)d_in[5];
  const float* w2 = (const float*)d_in[6];
  const float* b2 = (const float*)d_in[7];
  const float* ln1_g = (const float*)d_in[8];
  const float* ln1_b = (const float*)d_in[9];
  const float* ln2_g = (const float*)d_in[10];
  const float* ln2_b = (const float*)d_in[11];
  const float* head_ln_g = (const float*)d_in[12];
  const float* head_ln_b = (const float*)d_in[13];
  const float* head_w1 = (const float*)d_in[14];
  const float* head_b1 = (const float*)d_in[15];
  const float* head_w2 = (const float*)d_in[16];
  const float* head_b2 = (const float*)d_in[17];
  const float* gate_w = (const float*)d_in[18];
  const float* gate_b = (const float*)d_in[19];
  const float* gatec_w = (const float*)d_in[20];
  const float* gatec_b = (const float*)d_in[21];

  const size_t NTOK = 2 * S_LEN;
  const size_t SZ_BSD = NTOK * DMODEL;

  char* ws = (char*)d_ws;
  float* h = (float*)ws;                       ws += SZ_BSD * 4;
  u16* y = (u16*)ws;                           ws += SZ_BSD * 2;
  u16* attno = (u16*)ws;                       ws += SZ_BSD * 2;
  u16* big = (u16*)ws;                         ws += NTOK * FFDIM * 2;
  u16* t1 = (u16*)ws;                          ws += NTOK * (DMODEL / 2) * 2;
  u16* wqkv_t = (u16*)ws;                      ws += (size_t)3 * DMODEL * DMODEL * 2;
  u16* wout_t = (u16*)ws;                      ws += (size_t)DMODEL * DMODEL * 2;
  u16* w1_t = (u16*)ws;                        ws += (size_t)DMODEL * FFDIM * 2;
  u16* w2_t = (u16*)ws;                        ws += (size_t)DMODEL * FFDIM * 2;
  u16* hw1_t = (u16*)ws;                       ws += (size_t)DMODEL * (DMODEL / 2) * 2;

  hipMemcpyAsync(h, x, SZ_BSD * sizeof(float), hipMemcpyDeviceToDevice, stream);

  for (int l = 0; l < NLAYER; l++) {
    transpose_cast<<<dim3(3 * DMODEL / 32, DMODEL / 32), 256, 0, stream>>>(
        qkv_w + (size_t)l * DMODEL * 3 * DMODEL, wqkv_t, DMODEL, 3 * DMODEL);
    transpose_cast<<<dim3(DMODEL / 32, DMODEL / 32), 256, 0, stream>>>(
        out_w + (size_t)l * DMODEL * DMODEL, wout_t, DMODEL, DMODEL);
    transpose_cast<<<dim3(FFDIM / 32, DMODEL / 32), 256, 0, stream>>>(
        w1 + (size_t)l * DMODEL * FFDIM, w1_t, DMODEL, FFDIM);
    transpose_cast<<<dim3(DMODEL / 32, FFDIM / 32), 256, 0, stream>>>(
        w2 + (size_t)l * FFDIM * DMODEL, w2_t, FFDIM, DMODEL);

    ln_kernel<<<NTOK, 256, 0, stream>>>(h, ln1_g + l * DMODEL, ln1_b + l * DMODEL, y);
    mfma_gemm<128, 8, 1><<<dim3(3 * DMODEL / 128, NTOK / 128), 256, 0, stream>>>(
        y, wqkv_t, nullptr, big, nullptr, NTOK, 3 * DMODEL, DMODEL);
    fattn_kernel<<<dim3(S_LEN / 64, NHEAD, 2), 256, 0, stream>>>(
        big, tb, attno, (l % 2 == 0) ? 1 : 0);
    mfma_gemm<64, 4, 2><<<dim3(DMODEL / 64, NTOK / 128, 2), 256, 0, stream>>>(
        attno, wout_t, nullptr, nullptr, h, NTOK, DMODEL, DMODEL);
    ln_kernel<<<NTOK, 256, 0, stream>>>(h, ln2_g + l * DMODEL, ln2_b + l * DMODEL, y);
    mfma_gemm<128, 1 | 2 | 8, 1><<<dim3(FFDIM / 128, NTOK / 128), 256, 0, stream>>>(
        y, w1_t, b1 + (size_t)l * FFDIM, big, nullptr, NTOK, FFDIM, DMODEL);
    mfma_gemm<64, 1 | 4, 2><<<dim3(DMODEL / 64, NTOK / 128, 2), 256, 0, stream>>>(
        big, w2_t, b2 + (size_t)l * DMODEL, nullptr, h, NTOK, DMODEL, FFDIM);
  }

  transpose_cast<<<dim3((DMODEL / 2) / 32, DMODEL / 32), 256, 0, stream>>>(
      head_w1, hw1_t, DMODEL, DMODEL / 2);
  ln_kernel<<<NTOK, 256, 0, stream>>>(h, head_ln_g, head_ln_b, y);
  mfma_gemm<64, 1 | 2 | 8, 1><<<dim3((DMODEL / 2) / 64, NTOK / 128), 256, 0, stream>>>(
      y, hw1_t, head_b1, t1, nullptr, NTOK, DMODEL / 2, DMODEL);
  head_kernel<<<NTOK, 256, 0, stream>>>(h, t1, head_w2, head_b2,
                                        gate_w, gate_b, gatec_w, gatec_b,
                                        (float*)d_out);
}

// Round 9
// 1132.828 us; speedup vs baseline: 7.4428x; 1.1166x over previous
//
#include <hip/hip_runtime.h>
#include <math.h>

#define S_LEN 1024
#define DMODEL 1024
#define NHEAD 16
#define DHEAD 64
#define NLAYER 4
#define FFDIM 4096
#define WIN_HALF 128
#define LN_EPS 1e-5f

typedef unsigned short u16;
typedef __attribute__((ext_vector_type(8))) short short8;
typedef __attribute__((ext_vector_type(4))) float f32x4;

__device__ __forceinline__ u16 f2bf(float f) {
  union { float f; unsigned u; } v; v.f = f;
  unsigned r = v.u + 0x7fffu + ((v.u >> 16) & 1u);
  return (u16)(r >> 16);
}
__device__ __forceinline__ float bf2f(u16 u) {
  union { unsigned u; float f; } v; v.u = ((unsigned)u) << 16;
  return v.f;
}
__device__ __forceinline__ float gelu_exact(float x) {
  return 0.5f * x * (1.0f + erff(x * 0.70710678118654752f));
}
__device__ __forceinline__ void gload_lds16(const void* g, void* l) {
  __builtin_amdgcn_global_load_lds(
      (const __attribute__((address_space(1))) unsigned int*)g,
      (__attribute__((address_space(3))) unsigned int*)l, 16, 0, 0);
}

// ---------------------------------------------------------------- LayerNorm (fp32 in, bf16 out)
__global__ __launch_bounds__(256) void ln_kernel(
    const float* __restrict__ x, const float* __restrict__ g,
    const float* __restrict__ b, u16* __restrict__ y) {
  __shared__ float red[8];
  const int row = blockIdx.x;
  const int t = threadIdx.x;
  float4 v = ((const float4*)(x + (size_t)row * DMODEL))[t];
  float s = v.x + v.y + v.z + v.w;
  float ss = v.x * v.x + v.y * v.y + v.z * v.z + v.w * v.w;
#pragma unroll
  for (int o = 32; o > 0; o >>= 1) {
    s += __shfl_down(s, o);
    ss += __shfl_down(ss, o);
  }
  const int wid = t >> 6;
  if ((t & 63) == 0) { red[wid] = s; red[4 + wid] = ss; }
  __syncthreads();
  if (t == 0) {
    float S1 = red[0] + red[1] + red[2] + red[3];
    float S2 = red[4] + red[5] + red[6] + red[7];
    float m = S1 * (1.0f / DMODEL);
    float var = S2 * (1.0f / DMODEL) - m * m;
    red[0] = m;
    red[1] = rsqrtf(var + LN_EPS);
  }
  __syncthreads();
  const float m = red[0], inv = red[1];
  float4 gv = ((const float4*)g)[t];
  float4 bv = ((const float4*)b)[t];
  ushort4 o4;
  o4.x = f2bf((v.x - m) * inv * gv.x + bv.x);
  o4.y = f2bf((v.y - m) * inv * gv.y + bv.y);
  o4.z = f2bf((v.z - m) * inv * gv.z + bv.z);
  o4.w = f2bf((v.w - m) * inv * gv.w + bv.w);
  *(ushort4*)(y + (size_t)row * DMODEL + t * 4) = o4;
}

// ---------------------------------------------------------------- transpose+cast: W[K][N] f32 -> Wt[N][K] bf16
__global__ __launch_bounds__(256) void transpose_cast(
    const float* __restrict__ W, u16* __restrict__ Wt, int K, int N) {
  __shared__ float t[32][33];
  const int nb = blockIdx.x * 32, kb = blockIdx.y * 32;
  const int tx = threadIdx.x & 31, ty = threadIdx.x >> 5;
#pragma unroll
  for (int i = 0; i < 4; i++)
    t[ty + i * 8][tx] = W[(size_t)(kb + ty + i * 8) * N + nb + tx];
  __syncthreads();
#pragma unroll
  for (int i = 0; i < 4; i++)
    Wt[(size_t)(nb + ty + i * 8) * K + kb + tx] = f2bf(t[tx][ty + i * 8]);
}

// ---------------------------------------------------------------- bf16 MFMA GEMM
// C[M,N] = A[M,K](bf16) @ Bt[N,K]^T(bf16), fp32 accumulate.
// FLAGS: 1=bias, 2=gelu, 4=residual(+= into Cf fp32), 8=bf16 out (Cb)
// KS>1: split-K via atomicAdd into Cf
template <int BN, int FLAGS, int KS>
__global__ __launch_bounds__(256) void mfma_gemm(
    const u16* __restrict__ A, const u16* __restrict__ Bt,
    const float* __restrict__ bias, u16* __restrict__ Cb,
    float* __restrict__ Cf, int M, int N, int K) {
  constexpr int WAVES_M = (BN == 128) ? 2 : 4;
  constexpr int WAVES_N = 4 / WAVES_M;
  constexpr int MF = 128 / (WAVES_M * 16);
  constexpr int NF = BN / (WAVES_N * 16);
  __shared__ __align__(16) u16 As[128 * 32];
  __shared__ __align__(16) u16 Bs[BN * 32];

  const int tid = threadIdx.x;
  const int wid = tid >> 6, lane = tid & 63;
  const int wr = wid / WAVES_N, wc = wid % WAVES_N;
  const int row0 = blockIdx.y * 128, col0 = blockIdx.x * BN;
  const int kz = blockIdx.z;
  const int kbeg = kz * (K / KS), kend = kbeg + K / KS;

  const int frow = lane & 15, fk = (lane >> 4) * 8;
  const int lr = lane >> 2, lk8 = (lane & 3) * 8;

  f32x4 acc[MF][NF];
#pragma unroll
  for (int m = 0; m < MF; m++)
#pragma unroll
    for (int n = 0; n < NF; n++) acc[m][n] = (f32x4){0.f, 0.f, 0.f, 0.f};

  for (int kt = kbeg; kt < kend; kt += 32) {
    __syncthreads();
#pragma unroll
    for (int i = 0; i < 2; i++) {
      const int seg = i * 4 + wid;
      const int r = seg * 16 + lr;
      gload_lds16(A + (size_t)(row0 + r) * K + kt + lk8, (void*)(As + seg * 512));
    }
#pragma unroll
    for (int i = 0; i < BN / 64; i++) {
      const int seg = i * 4 + wid;
      const int r = seg * 16 + lr;
      gload_lds16(Bt + (size_t)(col0 + r) * K + kt + lk8, (void*)(Bs + seg * 512));
    }
    __syncthreads();

    short8 af[MF], bfr[NF];
#pragma unroll
    for (int m = 0; m < MF; m++)
      af[m] = *(const short8*)(As + (wr * MF * 16 + m * 16 + frow) * 32 + fk);
#pragma unroll
    for (int n = 0; n < NF; n++)
      bfr[n] = *(const short8*)(Bs + (wc * NF * 16 + n * 16 + frow) * 32 + fk);
#pragma unroll
    for (int m = 0; m < MF; m++)
#pragma unroll
      for (int n = 0; n < NF; n++)
        acc[m][n] = __builtin_amdgcn_mfma_f32_16x16x32_bf16(af[m], bfr[n], acc[m][n], 0, 0, 0);
  }

  const int crow0 = row0 + wr * (MF * 16);
  const int ccol0 = col0 + wc * (NF * 16);
#pragma unroll
  for (int m = 0; m < MF; m++) {
#pragma unroll
    for (int n = 0; n < NF; n++) {
      const int col = ccol0 + n * 16 + (lane & 15);
      const float bv = ((FLAGS & 1) && (KS == 1 || kz == 0)) ? bias[col] : 0.f;
#pragma unroll
      for (int j = 0; j < 4; j++) {
        const int row = crow0 + m * 16 + (lane >> 4) * 4 + j;
        float e = acc[m][n][j] + bv;
        if (FLAGS & 2) e = gelu_exact(e);
        if (KS > 1) {
          atomicAdd(Cf + (size_t)row * N + col, e);
        } else if (FLAGS & 4) {
          float* p = Cf + (size_t)row * N + col;
          *p += e;
        } else if (FLAGS & 8) {
          Cb[(size_t)row * N + col] = f2bf(e);
        } else {
          Cf[(size_t)row * N + col] = e;
        }
      }
    }
  }
}

// ---------------------------------------------------------------- MFMA flash attention
// Block = (64 q, head, batch), 4 waves x 16 q-rows. QK^T and PV on matrix cores.
// K staged via gload_lds w/ pre-swizzled SOURCE (linear dest, m173 pattern);
// bias tile staged via gload_lds into per-wave LDS (coalesced, latency hidden
// under the post-staging barrier drain); V reg-transposed into swizzled LDS.
__global__ __launch_bounds__(256) void fattn_kernel(
    const u16* __restrict__ qkv, const float* __restrict__ bias,
    u16* __restrict__ out, int use_window) {
  __shared__ __align__(16) u16 Kl[64 * 64];      // [key][d], swizzled
  __shared__ __align__(16) u16 Vt[64 * 64];      // [d][key], swizzled
  __shared__ __align__(16) u16 Pl[4][16 * 64];   // per-wave [q][k], swizzled
  __shared__ __align__(16) float Bl[4][1024];    // per-wave bias [16 q][64 k]

  const int b = blockIdx.z, h = blockIdx.y;
  const int qt = (b == 0) ? blockIdx.x : ((int)gridDim.x - 1 - (int)blockIdx.x);
  const int q0 = qt << 6;
  const int tid = threadIdx.x;
  const int wid = tid >> 6, l = tid & 63;
  const int lg = l >> 4, l15 = l & 15, l7 = l & 7;

  const u16* qbase = qkv + (size_t)b * S_LEN * (3 * DMODEL) + h * DHEAD;
  const u16* kbase = qbase + DMODEL;
  const u16* vbase = qbase + 2 * DMODEL;
  const float* bbase = bias + (size_t)(b * NHEAD + h) * S_LEN * S_LEN;

  const int qw = q0 + wid * 16;

  short8 aQ[2];
#pragma unroll
  for (int ds = 0; ds < 2; ds++)
    aQ[ds] = *(const short8*)(qbase + (size_t)(qw + l15) * (3 * DMODEL) + ds * 32 + lg * 8);

  f32x4 o[4];
#pragma unroll
  for (int dt = 0; dt < 4; dt++) o[dt] = (f32x4){0.f, 0.f, 0.f, 0.f};
  float mr[4] = {-1e30f, -1e30f, -1e30f, -1e30f};
  float lrw[4] = {0.f, 0.f, 0.f, 0.f};

  // K gload source pre-swizzle: lane l fills LDS row seg*8+(l>>3), slot l&7;
  // content must be chunk (l&7)^((l>>3)&7) so reads at slot=chunk^(row&7) land.
  const int kgrow = l >> 3;
  const int kgchunk = (l & 7) ^ (kgrow & 7);
  // bias gload: lane l covers row s*4+(l>>4), 4 floats at col (l&15)*4
  const int bgrow = l >> 4;
  // V transpose staging
  const int vk = tid >> 2, vc1 = tid & 3;

  const int lo_t = use_window ? max(0, qt - 2) : 0;
  const int hi_t = qt;

  for (int kt = lo_t; kt <= hi_t; kt++) {
    const int k0 = kt << 6;
    __syncthreads();  // previous tile's LDS reads complete

    // async: K tile (2 gloads/thread, pre-swizzled source)
#pragma unroll
    for (int i = 0; i < 2; i++) {
      const int seg = i * 4 + wid;
      gload_lds16(kbase + (size_t)(k0 + seg * 8 + kgrow) * (3 * DMODEL) + kgchunk * 8,
                  (void*)(Kl + seg * 512));
    }
    // async: bias tile for this wave's 16 q-rows (4 gloads/thread)
#pragma unroll
    for (int s = 0; s < 4; s++) {
      gload_lds16(bbase + (size_t)(qw + s * 4 + bgrow) * S_LEN + k0 + l15 * 4,
                  (void*)(&Bl[wid][s * 256]));
    }
    // V: global->reg->LDS transpose (scalar, swizzled)
    {
      short8 g1 = *(const short8*)(vbase + (size_t)(k0 + vk) * (3 * DMODEL) + vc1 * 8);
      short8 g2 = *(const short8*)(vbase + (size_t)(k0 + vk) * (3 * DMODEL) + (vc1 + 4) * 8);
#pragma unroll
      for (int i = 0; i < 8; i++) {
        const int d1 = vc1 * 8 + i, d2 = d1 + 32;
        Vt[d1 * 64 + (vk ^ ((d1 >> 3) << 3))] = (u16)(unsigned short)g1[i];
        Vt[d2 * 64 + (vk ^ ((d2 >> 3) << 3))] = (u16)(unsigned short)g2[i];
      }
    }
    __syncthreads();  // drains vmcnt (K+bias gloads) + lgkmcnt (V writes)

    // S = Q K^T  (C: row q = lg*4+j, col k = n*16+l15)
    f32x4 s[4];
#pragma unroll
    for (int n = 0; n < 4; n++) s[n] = (f32x4){0.f, 0.f, 0.f, 0.f};
#pragma unroll
    for (int ds = 0; ds < 2; ds++) {
#pragma unroll
      for (int n = 0; n < 4; n++) {
        const int key = n * 16 + l15;
        short8 bK = ((const short8*)Kl)[key * 8 + ((ds * 4 + lg) ^ l7)];
        s[n] = __builtin_amdgcn_mfma_f32_16x16x32_bf16(aQ[ds], bK, s[n], 0, 0, 0);
      }
    }

    // bias (from LDS) + mask + online softmax; P -> bf16 in per-wave LDS
#pragma unroll
    for (int j = 0; j < 4; j++) {
      const int q = qw + lg * 4 + j;
      float sv[4];
#pragma unroll
      for (int n = 0; n < 4; n++) {
        const int k = k0 + n * 16 + l15;
        const float bb = Bl[wid][lg * 256 + j * 64 + n * 16 + l15];
        const float x = s[n][j] * 0.125f + bb;
        const bool valid = (k <= q) && (!use_window || (q - k) <= WIN_HALF);
        sv[n] = valid ? x : -1e30f;
      }
      float pm = fmaxf(fmaxf(sv[0], sv[1]), fmaxf(sv[2], sv[3]));
      pm = fmaxf(pm, __shfl_xor(pm, 1));
      pm = fmaxf(pm, __shfl_xor(pm, 2));
      pm = fmaxf(pm, __shfl_xor(pm, 4));
      pm = fmaxf(pm, __shfl_xor(pm, 8));
      const float mnew = fmaxf(mr[j], pm);
      const float alpha = __expf(mr[j] - mnew);
      mr[j] = mnew;
      const int qloc = lg * 4 + j;
      float ps = 0.f;
#pragma unroll
      for (int n = 0; n < 4; n++) {
        const float p = __expf(sv[n] - mnew);
        ps += p;
        Pl[wid][qloc * 64 + ((n * 16 + l15) ^ ((qloc & 7) << 3))] = f2bf(p);
      }
      ps += __shfl_xor(ps, 1);
      ps += __shfl_xor(ps, 2);
      ps += __shfl_xor(ps, 4);
      ps += __shfl_xor(ps, 8);
      lrw[j] = lrw[j] * alpha + ps;
#pragma unroll
      for (int dt = 0; dt < 4; dt++) o[dt][j] *= alpha;
    }

    // cross-lane P handoff through LDS within the wave
    asm volatile("s_waitcnt lgkmcnt(0)" ::: "memory");
    __builtin_amdgcn_sched_barrier(0);

    // O += P V  (A rows = q, B rows = d)
#pragma unroll
    for (int ks = 0; ks < 2; ks++) {
      short8 aP = ((const short8*)Pl[wid])[l15 * 8 + ((ks * 4 + lg) ^ l7)];
#pragma unroll
      for (int dt = 0; dt < 4; dt++) {
        const int d = dt * 16 + l15;
        short8 bV = ((const short8*)Vt)[d * 8 + ((ks * 4 + lg) ^ (d >> 3))];
        o[dt] = __builtin_amdgcn_mfma_f32_16x16x32_bf16(aP, bV, o[dt], 0, 0, 0);
      }
    }
  }

#pragma unroll
  for (int j = 0; j < 4; j++) {
    const float inv = 1.0f / lrw[j];
    const int q = qw + lg * 4 + j;
    u16* orow = out + (size_t)(b * S_LEN + q) * DMODEL + h * DHEAD;
#pragma unroll
    for (int dt = 0; dt < 4; dt++) orow[dt * 16 + l15] = f2bf(o[dt][j] * inv);
  }
}

// ---------------------------------------------------------------- Head + gate
__global__ __launch_bounds__(256) void head_kernel(
    const float* __restrict__ h, const u16* __restrict__ t1,
    const float* __restrict__ w2, const float* __restrict__ b2,
    const float* __restrict__ gate_w, const float* __restrict__ gate_b,
    const float* __restrict__ gatec_w, const float* __restrict__ gatec_b,
    float* __restrict__ out) {
  __shared__ float redm[4][8];
  const int row = blockIdx.x;
  const int t = threadIdx.x;
  const float* hrow = h + (size_t)row * DMODEL;
  const u16* trow = t1 + (size_t)row * (DMODEL / 2);

  float p[8] = {0, 0, 0, 0, 0, 0, 0, 0};
  for (int i = t; i < DMODEL / 2; i += 256) {
    float tv = bf2f(trow[i]);
#pragma unroll
    for (int j = 0; j < 7; j++) p[j] += tv * w2[i * 7 + j];
  }
  for (int i = t; i < DMODEL; i += 256) p[7] += hrow[i] * gate_w[i];

#pragma unroll
  for (int j = 0; j < 8; j++) {
#pragma unroll
    for (int o = 32; o > 0; o >>= 1) p[j] += __shfl_down(p[j], o);
  }
  const int wid = t >> 6;
  if ((t & 63) == 0) {
#pragma unroll
    for (int j = 0; j < 8; j++) redm[wid][j] = p[j];
  }
  __syncthreads();

  float raw[7], gd = 0.f;
#pragma unroll
  for (int j = 0; j < 7; j++)
    raw[j] = redm[0][j] + redm[1][j] + redm[2][j] + redm[3][j] + b2[j];
  gd = redm[0][7] + redm[1][7] + redm[2][7] + redm[3][7] + gate_b[0];

  float sig[7];
#pragma unroll
  for (int j = 0; j < 7; j++) sig[j] = 1.0f / (1.0f + __expf(-raw[j]));
  const float learned = 1.0f / (1.0f + __expf(-gd));
  const float s2v = tanhf(raw[2]) * 2.0f;
  const float gate =
      1.0f / (1.0f + __expf(-(learned * gatec_w[0] + sig[0] * gatec_w[1] + gatec_b[0])));

  float* orow = out + (size_t)row * (DMODEL + 8);
  float4 hv = ((const float4*)hrow)[t];
  *(float4*)(orow + t * 4) = hv;
  if (t == 0) {
    orow[DMODEL + 0] = sig[0];
    orow[DMODEL + 1] = sig[1];
    orow[DMODEL + 2] = s2v;
    orow[DMODEL + 3] = sig[3];
    orow[DMODEL + 4] = sig[4];
    orow[DMODEL + 5] = sig[5];
    orow[DMODEL + 6] = sig[6];
    orow[DMODEL + 7] = gate;
  }
}

// ---------------------------------------------------------------- launch
extern "C" void kernel_launch(void* const* d_in, const int* in_sizes, int n_in,
                              void* d_out, int out_size, void* d_ws, size_t ws_size,
                              hipStream_t stream) {
  const float* x = (const float*)d_in[0];
  const float* tb = (const float*)d_in[1];
  const float* qkv_w = (const float*)d_in[2];
  const float* out_w = (const float*)d_in[3];
  const float* w1 = (const float*)d_in[4];
  const float* b1 = (const float*)d_in[5];
  const float* w2 = (const float*)d_in[6];
  const float* b2 = (const float*)d_in[7];
  const float* ln1_g = (const float*)d_in[8];
  const float* ln1_b = (const float*)d_in[9];
  const float* ln2_g = (const float*)d_in[10];
  const float* ln2_b = (const float*)d_in[11];
  const float* head_ln_g = (const float*)d_in[12];
  const float* head_ln_b = (const float*)d_in[13];
  const float* head_w1 = (const float*)d_in[14];
  const float* head_b1 = (const float*)d_in[15];
  const float* head_w2 = (const float*)d_in[16];
  const float* head_b2 = (const float*)d_in[17];
  const float* gate_w = (const float*)d_in[18];
  const float* gate_b = (const float*)d_in[19];
  const float* gatec_w = (const float*)d_in[20];
  const float* gatec_b = (const float*)d_in[21];

  const size_t NTOK = 2 * S_LEN;
  const size_t SZ_BSD = NTOK * DMODEL;

  char* ws = (char*)d_ws;
  float* h = (float*)ws;                       ws += SZ_BSD * 4;
  u16* y = (u16*)ws;                           ws += SZ_BSD * 2;
  u16* attno = (u16*)ws;                       ws += SZ_BSD * 2;
  u16* big = (u16*)ws;                         ws += NTOK * FFDIM * 2;
  u16* t1 = (u16*)ws;                          ws += NTOK * (DMODEL / 2) * 2;
  u16* wqkv_t = (u16*)ws;                      ws += (size_t)3 * DMODEL * DMODEL * 2;
  u16* wout_t = (u16*)ws;                      ws += (size_t)DMODEL * DMODEL * 2;
  u16* w1_t = (u16*)ws;                        ws += (size_t)DMODEL * FFDIM * 2;
  u16* w2_t = (u16*)ws;                        ws += (size_t)DMODEL * FFDIM * 2;
  u16* hw1_t = (u16*)ws;                       ws += (size_t)DMODEL * (DMODEL / 2) * 2;

  hipMemcpyAsync(h, x, SZ_BSD * sizeof(float), hipMemcpyDeviceToDevice, stream);

  for (int l = 0; l < NLAYER; l++) {
    transpose_cast<<<dim3(3 * DMODEL / 32, DMODEL / 32), 256, 0, stream>>>(
        qkv_w + (size_t)l * DMODEL * 3 * DMODEL, wqkv_t, DMODEL, 3 * DMODEL);
    transpose_cast<<<dim3(DMODEL / 32, DMODEL / 32), 256, 0, stream>>>(
        out_w + (size_t)l * DMODEL * DMODEL, wout_t, DMODEL, DMODEL);
    transpose_cast<<<dim3(FFDIM / 32, DMODEL / 32), 256, 0, stream>>>(
        w1 + (size_t)l * DMODEL * FFDIM, w1_t, DMODEL, FFDIM);
    transpose_cast<<<dim3(DMODEL / 32, FFDIM / 32), 256, 0, stream>>>(
        w2 + (size_t)l * FFDIM * DMODEL, w2_t, FFDIM, DMODEL);

    ln_kernel<<<NTOK, 256, 0, stream>>>(h, ln1_g + l * DMODEL, ln1_b + l * DMODEL, y);
    mfma_gemm<128, 8, 1><<<dim3(3 * DMODEL / 128, NTOK / 128), 256, 0, stream>>>(
        y, wqkv_t, nullptr, big, nullptr, NTOK, 3 * DMODEL, DMODEL);
    fattn_kernel<<<dim3(S_LEN / 64, NHEAD, 2), 256, 0, stream>>>(
        big, tb, attno, (l % 2 == 0) ? 1 : 0);
    mfma_gemm<64, 4, 2><<<dim3(DMODEL / 64, NTOK / 128, 2), 256, 0, stream>>>(
        attno, wout_t, nullptr, nullptr, h, NTOK, DMODEL, DMODEL);
    ln_kernel<<<NTOK, 256, 0, stream>>>(h, ln2_g + l * DMODEL, ln2_b + l * DMODEL, y);
    mfma_gemm<128, 1 | 2 | 8, 1><<<dim3(FFDIM / 128, NTOK / 128), 256, 0, stream>>>(
        y, w1_t, b1 + (size_t)l * FFDIM, big, nullptr, NTOK, FFDIM, DMODEL);
    mfma_gemm<64, 1 | 4, 2><<<dim3(DMODEL / 64, NTOK / 128, 2), 256, 0, stream>>>(
        big, w2_t, b2 + (size_t)l * DMODEL, nullptr, h, NTOK, DMODEL, FFDIM);
  }

  transpose_cast<<<dim3((DMODEL / 2) / 32, DMODEL / 32), 256, 0, stream>>>(
      head_w1, hw1_t, DMODEL, DMODEL / 2);
  ln_kernel<<<NTOK, 256, 0, stream>>>(h, head_ln_g, head_ln_b, y);
  mfma_gemm<64, 1 | 2 | 8, 1><<<dim3((DMODEL / 2) / 64, NTOK / 128), 256, 0, stream>>>(
      y, hw1_t, head_b1, t1, nullptr, NTOK, DMODEL / 2, DMODEL);
  head_kernel<<<NTOK, 256, 0, stream>>>(h, t1, head_w2, head_b2,
                                        gate_w, gate_b, gatec_w, gatec_b,
                                        (float*)d_out);
}